// Round 12
// baseline (283.774 us; speedup 1.0000x reference)
//
#include <hip/hip_runtime.h>

#define NN 100000
#define NE 1600000
#define D  64
#define BSH 8                                  // bucket shift: 256 nodes/bucket
#define NBKT ((NN + 255) >> BSH)               // 391
#define NBLK_E ((NE / 4 + 1023) / 1024)        // 391 blocks, 1024 int4s each
#define H_SCALE 256.0f
#define H_ISCALE 0.00390625f

typedef __attribute__((ext_vector_type(8))) short short8v;
typedef __attribute__((ext_vector_type(4))) unsigned short ushort4v;
typedef __attribute__((ext_vector_type(4))) float f32x4;
typedef __attribute__((ext_vector_type(2))) float f32x2;

__device__ __forceinline__ float bf2f(unsigned short x) {
    return __uint_as_float(((unsigned)x) << 16);
}
__device__ __forceinline__ unsigned short f2bf(float f) {  // RNE
    unsigned u = __float_as_uint(f);
    return (unsigned short)((u + 0x7fff + ((u >> 16) & 1)) >> 16);
}

// ---- fused prep: W1/W2 -> bf16, cvec, zero ghist ----
__global__ __launch_bounds__(256) void k_prep(
        const float* __restrict__ W1, const float* __restrict__ W2,
        const float* __restrict__ W3, const float* __restrict__ W4,
        unsigned short* __restrict__ w1b, unsigned short* __restrict__ w2b,
        float* __restrict__ cvec, int* __restrict__ ghist) {
    int b = blockIdx.x, tid = threadIdx.x;
    if (b < 16) {
        int i = b * 256 + tid;
        w1b[i] = f2bf(W1[i]);
        w2b[i] = f2bf(W2[i]);
    } else {
        for (int i = tid; i < NBKT; i += 256) ghist[i] = 0;
        if (tid < 64) {
            float s = 0.f;
            for (int k = 0; k < D; ++k) {
                float w4 = W4[k];
                s += W3[tid * D + k] * (w4 > 0.f ? w4 : 0.f);
            }
            cvec[tid] = s;
        }
    }
}

// ---- pass A: global bucket histogram (LDS-staged) ----
__global__ __launch_bounds__(256) void k_hist(const int* __restrict__ row,
                                              int* __restrict__ ghist) {
    __shared__ int h[NBKT];
    int tid = threadIdx.x;
    for (int i = tid; i < NBKT; i += 256) h[i] = 0;
    __syncthreads();
    int base4 = blockIdx.x * 1024;
    #pragma unroll
    for (int k = 0; k < 4; ++k) {
        int i4 = base4 + k * 256 + tid;
        if (i4 < NE / 4) {
            int4 r = ((const int4*)row)[i4];
            atomicAdd(&h[r.x >> BSH], 1);
            atomicAdd(&h[r.y >> BSH], 1);
            atomicAdd(&h[r.z >> BSH], 1);
            atomicAdd(&h[r.w >> BSH], 1);
        }
    }
    __syncthreads();
    for (int i = tid; i < NBKT; i += 256) if (h[i]) atomicAdd(&ghist[i], h[i]);
}

// ---- pass B: exclusive scan of 391 bucket counts (1 block) ----
__global__ __launch_bounds__(256) void k_bscan(const int* __restrict__ ghist,
                                               int* __restrict__ bbase,
                                               int* __restrict__ bcur) {
    __shared__ int sc[2][512];
    int t = threadIdx.x;
    int cur = 0;
    #pragma unroll
    for (int k = 0; k < 2; ++k) {
        int i = t + k * 256;
        sc[0][i] = (i < NBKT) ? ghist[i] : 0;
    }
    __syncthreads();
    for (int s = 1; s < 512; s <<= 1) {
        #pragma unroll
        for (int k = 0; k < 2; ++k) {
            int i = t + k * 256;
            sc[cur ^ 1][i] = sc[cur][i] + ((i >= s) ? sc[cur][i - s] : 0);
        }
        cur ^= 1;
        __syncthreads();
    }
    #pragma unroll
    for (int k = 0; k < 2; ++k) {
        int i = t + k * 256;
        if (i < NBKT) {
            int b = (i == 0) ? 0 : sc[cur][i - 1];
            bbase[i] = b;
            bcur[i] = b;
        } else if (i == NBKT) {
            bbase[NBKT] = sc[cur][NBKT - 1];   // = NE
        }
    }
}

// ---- pass C: bucket-sort edges into packed u32 (lrow<<17 | col) ----
__global__ __launch_bounds__(256) void k_bucket(const int* __restrict__ row,
                                                const int* __restrict__ col,
                                                int* __restrict__ bcur,
                                                unsigned* __restrict__ sorted) {
    __shared__ int hist[NBKT];
    __shared__ int bbase_s[NBKT];
    int tid = threadIdx.x;
    for (int i = tid; i < NBKT; i += 256) hist[i] = 0;
    __syncthreads();
    int base4 = blockIdx.x * 1024;
    int4 r4[4], c4[4];
    int rank[16];
    bool valid[4];
    #pragma unroll
    for (int k = 0; k < 4; ++k) {
        int i4 = base4 + k * 256 + tid;
        valid[k] = (i4 < NE / 4);
        if (valid[k]) {
            r4[k] = ((const int4*)row)[i4];
            c4[k] = ((const int4*)col)[i4];
            rank[k * 4 + 0] = atomicAdd(&hist[r4[k].x >> BSH], 1);
            rank[k * 4 + 1] = atomicAdd(&hist[r4[k].y >> BSH], 1);
            rank[k * 4 + 2] = atomicAdd(&hist[r4[k].z >> BSH], 1);
            rank[k * 4 + 3] = atomicAdd(&hist[r4[k].w >> BSH], 1);
        }
    }
    __syncthreads();
    for (int i = tid; i < NBKT; i += 256)
        bbase_s[i] = hist[i] ? atomicAdd(&bcur[i], hist[i]) : 0;
    __syncthreads();
    #pragma unroll
    for (int k = 0; k < 4; ++k) {
        if (valid[k]) {
            int rr[4] = {r4[k].x, r4[k].y, r4[k].z, r4[k].w};
            int cc[4] = {c4[k].x, c4[k].y, c4[k].z, c4[k].w};
            #pragma unroll
            for (int j = 0; j < 4; ++j) {
                int b = rr[j] >> BSH;
                unsigned pk = ((unsigned)(rr[j] & 255) << 17) | (unsigned)cc[j];
                sorted[bbase_s[b] + rank[k * 4 + j]] = pk;
            }
        }
    }
}

// ---- pass D: per-bucket fine CSR (LDS count -> scan -> scatter) ----
__global__ __launch_bounds__(256) void k_fine(const unsigned* __restrict__ sorted,
                                              const int* __restrict__ bbase,
                                              int* __restrict__ csr_col,
                                              int* __restrict__ cnt_g,
                                              int2* __restrict__ se_g) {
    __shared__ int cnt_s[256];
    __shared__ int cur_s[256];
    __shared__ int sc[2][256];
    int b = blockIdx.x;
    int tid = threadIdx.x;
    int s0 = bbase[b], e0 = bbase[b + 1];
    cnt_s[tid] = 0;
    __syncthreads();
    for (int i = s0 + tid; i < e0; i += 256)
        atomicAdd(&cnt_s[sorted[i] >> 17], 1);
    __syncthreads();
    int cur = 0;
    sc[0][tid] = cnt_s[tid];
    __syncthreads();
    for (int s = 1; s < 256; s <<= 1) {
        sc[cur ^ 1][tid] = sc[cur][tid] + ((tid >= s) ? sc[cur][tid - s] : 0);
        cur ^= 1;
        __syncthreads();
    }
    int incl = sc[cur][tid];
    cur_s[tid] = incl - cnt_s[tid];           // exclusive offset
    int nb = NN - b * 256;
    nb = nb > 256 ? 256 : nb;
    if (tid < nb) {
        int node = b * 256 + tid;
        cnt_g[node] = cnt_s[tid];
        se_g[node] = make_int2(s0 + incl - cnt_s[tid], s0 + incl);
    }
    __syncthreads();
    for (int i = s0 + tid; i < e0; i += 256) {
        unsigned u = sorted[i];
        int p = atomicAdd(&cur_s[u >> 17], 1);
        csr_col[s0 + p] = (int)(u & 0x1FFFFu);
    }
}

// ---- base_bf = bf16(Xv@W1.T + deg*c) via MFMA; emb_bf = bf16(relu(.)) ----
__global__ __launch_bounds__(256) void k_base(
        const float* __restrict__ Xv, const unsigned short* __restrict__ w1b,
        const int* __restrict__ cnt, const float* __restrict__ cvec,
        unsigned short* __restrict__ base_bf, unsigned short* __restrict__ emb_bf) {
    int wid = blockIdx.x * 4 + (threadIdx.x >> 6);
    int lane = threadIdx.x & 63;
    int m0 = wid * 16;
    if (m0 >= NN) return;
    int r = lane & 15, half = lane >> 4;
    const float* arow = Xv + (size_t)(m0 + r) * D + half * 8;
    f32x4 xa = *(const f32x4*)(arow);
    f32x4 xb = *(const f32x4*)(arow + 4);
    f32x4 xc = *(const f32x4*)(arow + 32);
    f32x4 xd = *(const f32x4*)(arow + 36);
    short8v a0, a1;
    #pragma unroll
    for (int j = 0; j < 4; ++j) {
        a0[j]     = (short)f2bf(xa[j]);
        a0[j + 4] = (short)f2bf(xb[j]);
        a1[j]     = (short)f2bf(xc[j]);
        a1[j + 4] = (short)f2bf(xd[j]);
    }
    int4 c4 = *(const int4*)(cnt + m0 + half * 4);    // deg of the 4 C-rows this lane holds
    float dg[4] = {(float)c4.x, (float)c4.y, (float)c4.z, (float)c4.w};
    #pragma unroll
    for (int t = 0; t < 4; ++t) {
        short8v b0 = *(const short8v*)(w1b + (size_t)(t * 16 + r) * D + half * 8);
        short8v b1 = *(const short8v*)(w1b + (size_t)(t * 16 + r) * D + 32 + half * 8);
        f32x4 cacc = {0.f, 0.f, 0.f, 0.f};
        cacc = __builtin_amdgcn_mfma_f32_16x16x32_bf16(a0, b0, cacc, 0, 0, 0);
        cacc = __builtin_amdgcn_mfma_f32_16x16x32_bf16(a1, b1, cacc, 0, 0, 0);
        float cv = cvec[t * 16 + r];
        #pragma unroll
        for (int q = 0; q < 4; ++q) {
            float s = cacc[q] + dg[q] * cv;
            size_t idx = (size_t)(m0 + half * 4 + q) * D + t * 16 + r;
            base_bf[idx] = f2bf(s);
            emb_bf[idx] = f2bf(s > 0.f ? s : 0.f);
        }
    }
}

// ---- h planes = fp8_e4m3( (emb_bf @ W2bf.T) * H_SCALE ) via MFMA ----
// Plane p (p=0: ch 0..31, p=1: ch 32..63) stored contiguously: hp = h8 + p*NN*32;
// row n occupies hp[n*32 .. n*32+31]  (3.2 MB per plane -> fits per-XCD L2).
__global__ __launch_bounds__(256) void k_h(
        const unsigned short* __restrict__ emb_bf, const unsigned short* __restrict__ w2b,
        unsigned char* __restrict__ h8) {
    int wid = blockIdx.x * 4 + (threadIdx.x >> 6);
    int lane = threadIdx.x & 63;
    int m0 = wid * 16;
    if (m0 >= NN) return;
    int r = lane & 15, half = lane >> 4;
    const unsigned short* arow = emb_bf + (size_t)(m0 + r) * D + half * 8;
    short8v a0 = *(const short8v*)(arow);
    short8v a1 = *(const short8v*)(arow + 32);
    #pragma unroll
    for (int t = 0; t < 4; ++t) {
        short8v b0 = *(const short8v*)(w2b + (size_t)(t * 16 + r) * D + half * 8);
        short8v b1 = *(const short8v*)(w2b + (size_t)(t * 16 + r) * D + 32 + half * 8);
        f32x4 cacc = {0.f, 0.f, 0.f, 0.f};
        cacc = __builtin_amdgcn_mfma_f32_16x16x32_bf16(a0, b0, cacc, 0, 0, 0);
        cacc = __builtin_amdgcn_mfma_f32_16x16x32_bf16(a1, b1, cacc, 0, 0, 0);
        unsigned char* hp = h8 + (size_t)(t >> 1) * NN * 32;   // plane
        int ic = (t & 1) * 16 + r;                             // in-plane channel
        #pragma unroll
        for (int q = 0; q < 4; ++q) {
            int pk = __builtin_amdgcn_cvt_pk_fp8_f32(cacc[q] * H_SCALE, 0.f, 0, false);
            hp[(size_t)(m0 + half * 4 + q) * 32 + ic] = (unsigned char)(pk & 0xff);
        }
    }
}

// ---- half-channel pull pass over plane P ----
// emb[i][P*32..P*32+31] = relu(base + (1/S)*sum h_plane[col]); gather working
// set = 3.2 MB (fits 4 MiB per-XCD L2). 8 lanes/edge x uint (4ch), 16 edges in
// flight (2-trip unroll), 12 shfl_xor fold, 128B coalesced epilogue.
template<int P, int LAST>
__global__ __launch_bounds__(256) void k_pull_half(
        const int2* __restrict__ se_g,
        const int* __restrict__ csr_col, const unsigned char* __restrict__ h8,
        const unsigned short* __restrict__ base_bf,
        unsigned short* __restrict__ out_bf, float* __restrict__ out_f32) {
    const unsigned char* hp = h8 + (size_t)P * NN * 32;
    int tid = threadIdx.x;
    int wave = tid >> 6, lane = tid & 63;
    int g = lane >> 3, l = lane & 7;   // edge slot g (0..7); channel group l: ch 4l..4l+3
    for (int it = blockIdx.x; it < NN / 4; it += gridDim.x) {
        int node = it * 4 + wave;
        int2 se = se_g[node];
        int start = se.x, end = se.y;
        float a0 = 0.f, a1 = 0.f, a2 = 0.f, a3 = 0.f;
        for (int j = start; j < end; j += 16) {     // 16 edges per trip (2 x 8 slots)
            int e0 = j + g;
            int e1 = j + 8 + g;
            int c0 = (e0 < end) ? csr_col[e0] : -1;
            int c1 = (e1 < end) ? csr_col[e1] : -1;
            unsigned v0 = 0, v1 = 0;
            if (c0 >= 0) v0 = *((const unsigned*)(hp + (size_t)c0 * 32) + l);  // 32B/edge
            if (c1 >= 0) v1 = *((const unsigned*)(hp + (size_t)c1 * 32) + l);
            if (c0 >= 0) {
                f32x2 f0 = __builtin_amdgcn_cvt_pk_f32_fp8(v0, false);
                f32x2 f1 = __builtin_amdgcn_cvt_pk_f32_fp8(v0, true);
                a0 += f0.x; a1 += f0.y; a2 += f1.x; a3 += f1.y;
            }
            if (c1 >= 0) {
                f32x2 f0 = __builtin_amdgcn_cvt_pk_f32_fp8(v1, false);
                f32x2 f1 = __builtin_amdgcn_cvt_pk_f32_fp8(v1, true);
                a0 += f0.x; a1 += f0.y; a2 += f1.x; a3 += f1.y;
            }
        }
        // fold the 8 edge slots (lane bits 3,4,5): 12 shfl_xor
        a0 += __shfl_xor(a0, 8);  a1 += __shfl_xor(a1, 8);
        a2 += __shfl_xor(a2, 8);  a3 += __shfl_xor(a3, 8);
        a0 += __shfl_xor(a0, 16); a1 += __shfl_xor(a1, 16);
        a2 += __shfl_xor(a2, 16); a3 += __shfl_xor(a3, 16);
        a0 += __shfl_xor(a0, 32); a1 += __shfl_xor(a1, 32);
        a2 += __shfl_xor(a2, 32); a3 += __shfl_xor(a3, 32);
        if (g == 0) {   // 8 lanes: lane l covers global ch P*32 + 4l .. +3 (128B store)
            int ch = P * 32 + l * 4;
            ushort4v b4 = *(const ushort4v*)(base_bf + (size_t)node * D + ch);
            float r0 = fmaxf(fmaf(a0, H_ISCALE, bf2f(b4[0])), 0.f);
            float r1 = fmaxf(fmaf(a1, H_ISCALE, bf2f(b4[1])), 0.f);
            float r2 = fmaxf(fmaf(a2, H_ISCALE, bf2f(b4[2])), 0.f);
            float r3 = fmaxf(fmaf(a3, H_ISCALE, bf2f(b4[3])), 0.f);
            if (LAST) {
                f32x4 o4 = {r0, r1, r2, r3};
                *(f32x4*)(out_f32 + (size_t)node * D + ch) = o4;
            } else {
                ushort4v o4 = {f2bf(r0), f2bf(r1), f2bf(r2), f2bf(r3)};
                *(ushort4v*)(out_bf + (size_t)node * D + ch) = o4;
            }
        }
    }
}

extern "C" void kernel_launch(void* const* d_in, const int* in_sizes, int n_in,
                              void* d_out, int out_size, void* d_ws, size_t ws_size,
                              hipStream_t stream) {
    const float* Xv = (const float*)d_in[0];
    const int*   ei = (const int*)d_in[1];
    const float* W1 = (const float*)d_in[2];
    const float* W2 = (const float*)d_in[3];
    const float* W3 = (const float*)d_in[4];
    const float* W4 = (const float*)d_in[5];

    char* ws = (char*)d_ws;
    size_t off = 0;
    unsigned short* base_bf = (unsigned short*)(ws + off); off += (size_t)NN * D * 2; // 12.8 MB
    unsigned char* h8 = (unsigned char*)(ws + off);    off += (size_t)NN * D;      // 6.4 MB (2 planes)
    int* csr_col = (int*)(ws + off);                   off += (size_t)NE * 4;      // 6.4 MB
    int* cnt     = (int*)(ws + off);                   off += (size_t)NN * 4;
    int2* se_g   = (int2*)(ws + off);                  off += (size_t)NN * 8;
    int* ghist   = (int*)(ws + off);                   off += NBKT * 4;
    int* bbase   = (int*)(ws + off);                   off += (NBKT + 1) * 4;
    int* bcur    = (int*)(ws + off);                   off += NBKT * 4;
    float* cvec  = (float*)(ws + off);                 off += D * 4;
    unsigned short* w1b = (unsigned short*)(ws + off); off += D * D * 2;
    unsigned short* w2b = (unsigned short*)(ws + off); off += D * D * 2;
    unsigned* sorted = (unsigned*)(ws + off);          off += (size_t)NE * 4;      // 6.4 MB

    // intermediate bf16 emb lives in d_out's bytes (final step overwrites with fp32)
    unsigned short* emb_bf = (unsigned short*)d_out;
    float* emb_f32 = (float*)d_out;

    const int* row = ei;
    const int* col = ei + NE;

    // ---- prep (fused) + CSR build: two-level multisplit (dense writes) ----
    k_prep<<<17, 256, 0, stream>>>(W1, W2, W3, W4, w1b, w2b, cvec, ghist);
    k_hist<<<NBLK_E, 256, 0, stream>>>(row, ghist);
    k_bscan<<<1, 256, 0, stream>>>(ghist, bbase, bcur);
    k_bucket<<<NBLK_E, 256, 0, stream>>>(row, col, bcur, sorted);
    k_fine<<<NBKT, 256, 0, stream>>>(sorted, bbase, csr_col, cnt, se_g);

    // ---- base, emb1 = relu(base) ----
    k_base<<<(NN / 16 + 3) / 4, 256, 0, stream>>>(Xv, w1b, cnt, cvec, base_bf, emb_bf);

    // ---- 3 remaining message-passing steps (2 half-channel pull passes each) ----
    for (int t = 0; t < 3; ++t) {
        k_h<<<(NN / 16 + 3) / 4, 256, 0, stream>>>(emb_bf, w2b, h8);
        if (t < 2) {
            k_pull_half<0, 0><<<2048, 256, 0, stream>>>(se_g, csr_col, h8, base_bf, emb_bf, nullptr);
            k_pull_half<1, 0><<<2048, 256, 0, stream>>>(se_g, csr_col, h8, base_bf, emb_bf, nullptr);
        } else {
            k_pull_half<0, 1><<<2048, 256, 0, stream>>>(se_g, csr_col, h8, base_bf, nullptr, emb_f32);
            k_pull_half<1, 1><<<2048, 256, 0, stream>>>(se_g, csr_col, h8, base_bf, nullptr, emb_f32);
        }
    }
}

// Round 13
// 208.002 us; speedup vs baseline: 1.3643x; 1.3643x over previous
//
#include <hip/hip_runtime.h>

#define NN 100000
#define NE 1600000
#define D  64
#define BSH 8                                  // bucket shift: 256 nodes/bucket
#define NBKT ((NN + 255) >> BSH)               // 391
#define NBLK_E ((NE / 4 + 1023) / 1024)        // 391 blocks, 1024 int4s each
#define H_SCALE 256.0f
#define H_ISCALE 0.00390625f

typedef __attribute__((ext_vector_type(8))) short short8v;
typedef __attribute__((ext_vector_type(4))) unsigned short ushort4v;
typedef __attribute__((ext_vector_type(4))) float f32x4;
typedef __attribute__((ext_vector_type(2))) float f32x2;

__device__ __forceinline__ float bf2f(unsigned short x) {
    return __uint_as_float(((unsigned)x) << 16);
}
__device__ __forceinline__ unsigned short f2bf(float f) {  // RNE
    unsigned u = __float_as_uint(f);
    return (unsigned short)((u + 0x7fff + ((u >> 16) & 1)) >> 16);
}

// ---- fused prep: W1/W2 -> bf16, cvec, zero ghist ----
__global__ __launch_bounds__(256) void k_prep(
        const float* __restrict__ W1, const float* __restrict__ W2,
        const float* __restrict__ W3, const float* __restrict__ W4,
        unsigned short* __restrict__ w1b, unsigned short* __restrict__ w2b,
        float* __restrict__ cvec, int* __restrict__ ghist) {
    int b = blockIdx.x, tid = threadIdx.x;
    if (b < 16) {
        int i = b * 256 + tid;
        w1b[i] = f2bf(W1[i]);
        w2b[i] = f2bf(W2[i]);
    } else {
        for (int i = tid; i < NBKT; i += 256) ghist[i] = 0;
        if (tid < 64) {
            float s = 0.f;
            for (int k = 0; k < D; ++k) {
                float w4 = W4[k];
                s += W3[tid * D + k] * (w4 > 0.f ? w4 : 0.f);
            }
            cvec[tid] = s;
        }
    }
}

// ---- pass A: global bucket histogram (LDS-staged) ----
__global__ __launch_bounds__(256) void k_hist(const int* __restrict__ row,
                                              int* __restrict__ ghist) {
    __shared__ int h[NBKT];
    int tid = threadIdx.x;
    for (int i = tid; i < NBKT; i += 256) h[i] = 0;
    __syncthreads();
    int base4 = blockIdx.x * 1024;
    #pragma unroll
    for (int k = 0; k < 4; ++k) {
        int i4 = base4 + k * 256 + tid;
        if (i4 < NE / 4) {
            int4 r = ((const int4*)row)[i4];
            atomicAdd(&h[r.x >> BSH], 1);
            atomicAdd(&h[r.y >> BSH], 1);
            atomicAdd(&h[r.z >> BSH], 1);
            atomicAdd(&h[r.w >> BSH], 1);
        }
    }
    __syncthreads();
    for (int i = tid; i < NBKT; i += 256) if (h[i]) atomicAdd(&ghist[i], h[i]);
}

// ---- pass B: exclusive scan of 391 bucket counts (1 block) ----
__global__ __launch_bounds__(256) void k_bscan(const int* __restrict__ ghist,
                                               int* __restrict__ bbase,
                                               int* __restrict__ bcur) {
    __shared__ int sc[2][512];
    int t = threadIdx.x;
    int cur = 0;
    #pragma unroll
    for (int k = 0; k < 2; ++k) {
        int i = t + k * 256;
        sc[0][i] = (i < NBKT) ? ghist[i] : 0;
    }
    __syncthreads();
    for (int s = 1; s < 512; s <<= 1) {
        #pragma unroll
        for (int k = 0; k < 2; ++k) {
            int i = t + k * 256;
            sc[cur ^ 1][i] = sc[cur][i] + ((i >= s) ? sc[cur][i - s] : 0);
        }
        cur ^= 1;
        __syncthreads();
    }
    #pragma unroll
    for (int k = 0; k < 2; ++k) {
        int i = t + k * 256;
        if (i < NBKT) {
            int b = (i == 0) ? 0 : sc[cur][i - 1];
            bbase[i] = b;
            bcur[i] = b;
        } else if (i == NBKT) {
            bbase[NBKT] = sc[cur][NBKT - 1];   // = NE
        }
    }
}

// ---- pass C: bucket-sort edges into packed u32 (lrow<<17 | col) ----
__global__ __launch_bounds__(256) void k_bucket(const int* __restrict__ row,
                                                const int* __restrict__ col,
                                                int* __restrict__ bcur,
                                                unsigned* __restrict__ sorted) {
    __shared__ int hist[NBKT];
    __shared__ int bbase_s[NBKT];
    int tid = threadIdx.x;
    for (int i = tid; i < NBKT; i += 256) hist[i] = 0;
    __syncthreads();
    int base4 = blockIdx.x * 1024;
    int4 r4[4], c4[4];
    int rank[16];
    bool valid[4];
    #pragma unroll
    for (int k = 0; k < 4; ++k) {
        int i4 = base4 + k * 256 + tid;
        valid[k] = (i4 < NE / 4);
        if (valid[k]) {
            r4[k] = ((const int4*)row)[i4];
            c4[k] = ((const int4*)col)[i4];
            rank[k * 4 + 0] = atomicAdd(&hist[r4[k].x >> BSH], 1);
            rank[k * 4 + 1] = atomicAdd(&hist[r4[k].y >> BSH], 1);
            rank[k * 4 + 2] = atomicAdd(&hist[r4[k].z >> BSH], 1);
            rank[k * 4 + 3] = atomicAdd(&hist[r4[k].w >> BSH], 1);
        }
    }
    __syncthreads();
    for (int i = tid; i < NBKT; i += 256)
        bbase_s[i] = hist[i] ? atomicAdd(&bcur[i], hist[i]) : 0;
    __syncthreads();
    #pragma unroll
    for (int k = 0; k < 4; ++k) {
        if (valid[k]) {
            int rr[4] = {r4[k].x, r4[k].y, r4[k].z, r4[k].w};
            int cc[4] = {c4[k].x, c4[k].y, c4[k].z, c4[k].w};
            #pragma unroll
            for (int j = 0; j < 4; ++j) {
                int b = rr[j] >> BSH;
                unsigned pk = ((unsigned)(rr[j] & 255) << 17) | (unsigned)cc[j];
                sorted[bbase_s[b] + rank[k * 4 + j]] = pk;
            }
        }
    }
}

// ---- pass D: per-bucket fine CSR (LDS count -> scan -> scatter) ----
__global__ __launch_bounds__(256) void k_fine(const unsigned* __restrict__ sorted,
                                              const int* __restrict__ bbase,
                                              int* __restrict__ csr_col,
                                              int* __restrict__ cnt_g,
                                              int2* __restrict__ se_g) {
    __shared__ int cnt_s[256];
    __shared__ int cur_s[256];
    __shared__ int sc[2][256];
    int b = blockIdx.x;
    int tid = threadIdx.x;
    int s0 = bbase[b], e0 = bbase[b + 1];
    cnt_s[tid] = 0;
    __syncthreads();
    for (int i = s0 + tid; i < e0; i += 256)
        atomicAdd(&cnt_s[sorted[i] >> 17], 1);
    __syncthreads();
    int cur = 0;
    sc[0][tid] = cnt_s[tid];
    __syncthreads();
    for (int s = 1; s < 256; s <<= 1) {
        sc[cur ^ 1][tid] = sc[cur][tid] + ((tid >= s) ? sc[cur][tid - s] : 0);
        cur ^= 1;
        __syncthreads();
    }
    int incl = sc[cur][tid];
    cur_s[tid] = incl - cnt_s[tid];           // exclusive offset
    int nb = NN - b * 256;
    nb = nb > 256 ? 256 : nb;
    if (tid < nb) {
        int node = b * 256 + tid;
        cnt_g[node] = cnt_s[tid];
        se_g[node] = make_int2(s0 + incl - cnt_s[tid], s0 + incl);
    }
    __syncthreads();
    for (int i = s0 + tid; i < e0; i += 256) {
        unsigned u = sorted[i];
        int p = atomicAdd(&cur_s[u >> 17], 1);
        csr_col[s0 + p] = (int)(u & 0x1FFFFu);
    }
}

// ---- k_baseh: base_bf = bf16(Xv@W1.T + deg*c); emb_bf = bf16(relu(.));
//      fused step-1 h8 = fp8((relu-emb @ W2.T) * S) via per-wave LDS transpose ----
__global__ __launch_bounds__(256) void k_baseh(
        const float* __restrict__ Xv, const unsigned short* __restrict__ w1b,
        const unsigned short* __restrict__ w2b,
        const int* __restrict__ cnt, const float* __restrict__ cvec,
        unsigned short* __restrict__ base_bf, unsigned short* __restrict__ emb_bf,
        unsigned char* __restrict__ h8) {
    __shared__ unsigned short etile[4][16][72];   // per-wave 16x64 bf16 tile (+pad)
    int wv = threadIdx.x >> 6;
    int wid = blockIdx.x * 4 + wv;
    int lane = threadIdx.x & 63;
    int m0 = wid * 16;
    if (m0 >= NN) return;
    int r = lane & 15, half = lane >> 4;
    const float* arow = Xv + (size_t)(m0 + r) * D + half * 8;
    f32x4 xa = *(const f32x4*)(arow);
    f32x4 xb = *(const f32x4*)(arow + 4);
    f32x4 xc = *(const f32x4*)(arow + 32);
    f32x4 xd = *(const f32x4*)(arow + 36);
    short8v a0, a1;
    #pragma unroll
    for (int j = 0; j < 4; ++j) {
        a0[j]     = (short)f2bf(xa[j]);
        a0[j + 4] = (short)f2bf(xb[j]);
        a1[j]     = (short)f2bf(xc[j]);
        a1[j + 4] = (short)f2bf(xd[j]);
    }
    int4 c4 = *(const int4*)(cnt + m0 + half * 4);
    float dg[4] = {(float)c4.x, (float)c4.y, (float)c4.z, (float)c4.w};
    #pragma unroll
    for (int t = 0; t < 4; ++t) {
        short8v b0 = *(const short8v*)(w1b + (size_t)(t * 16 + r) * D + half * 8);
        short8v b1 = *(const short8v*)(w1b + (size_t)(t * 16 + r) * D + 32 + half * 8);
        f32x4 cacc = {0.f, 0.f, 0.f, 0.f};
        cacc = __builtin_amdgcn_mfma_f32_16x16x32_bf16(a0, b0, cacc, 0, 0, 0);
        cacc = __builtin_amdgcn_mfma_f32_16x16x32_bf16(a1, b1, cacc, 0, 0, 0);
        float cv = cvec[t * 16 + r];
        #pragma unroll
        for (int q = 0; q < 4; ++q) {
            float s = cacc[q] + dg[q] * cv;
            size_t idx = (size_t)(m0 + half * 4 + q) * D + t * 16 + r;
            unsigned short ebf = f2bf(s > 0.f ? s : 0.f);
            base_bf[idx] = f2bf(s);
            emb_bf[idx] = ebf;
            etile[wv][half * 4 + q][t * 16 + r] = ebf;   // stage for fused h
        }
    }
    // fused h (step 1): A-frags from LDS tile (identical layout to k_h's load)
    short8v ha0 = *(const short8v*)(&etile[wv][r][half * 8]);
    short8v ha1 = *(const short8v*)(&etile[wv][r][32 + half * 8]);
    #pragma unroll
    for (int t = 0; t < 4; ++t) {
        short8v b0 = *(const short8v*)(w2b + (size_t)(t * 16 + r) * D + half * 8);
        short8v b1 = *(const short8v*)(w2b + (size_t)(t * 16 + r) * D + 32 + half * 8);
        f32x4 cacc = {0.f, 0.f, 0.f, 0.f};
        cacc = __builtin_amdgcn_mfma_f32_16x16x32_bf16(ha0, b0, cacc, 0, 0, 0);
        cacc = __builtin_amdgcn_mfma_f32_16x16x32_bf16(ha1, b1, cacc, 0, 0, 0);
        #pragma unroll
        for (int q = 0; q < 4; ++q) {
            int pk = __builtin_amdgcn_cvt_pk_fp8_f32(cacc[q] * H_SCALE, 0.f, 0, false);
            h8[(size_t)(m0 + half * 4 + q) * D + t * 16 + r] = (unsigned char)(pk & 0xff);
        }
    }
}

// ---- h8 = fp8_e4m3( (emb_bf @ W2bf.T) * H_SCALE ) via MFMA, 16 nodes/wave ----
__global__ __launch_bounds__(256) void k_h(
        const unsigned short* __restrict__ emb_bf, const unsigned short* __restrict__ w2b,
        unsigned char* __restrict__ h8) {
    int wid = blockIdx.x * 4 + (threadIdx.x >> 6);
    int lane = threadIdx.x & 63;
    int m0 = wid * 16;
    if (m0 >= NN) return;
    int r = lane & 15, half = lane >> 4;
    const unsigned short* arow = emb_bf + (size_t)(m0 + r) * D + half * 8;
    short8v a0 = *(const short8v*)(arow);
    short8v a1 = *(const short8v*)(arow + 32);
    #pragma unroll
    for (int t = 0; t < 4; ++t) {
        short8v b0 = *(const short8v*)(w2b + (size_t)(t * 16 + r) * D + half * 8);
        short8v b1 = *(const short8v*)(w2b + (size_t)(t * 16 + r) * D + 32 + half * 8);
        f32x4 cacc = {0.f, 0.f, 0.f, 0.f};
        cacc = __builtin_amdgcn_mfma_f32_16x16x32_bf16(a0, b0, cacc, 0, 0, 0);
        cacc = __builtin_amdgcn_mfma_f32_16x16x32_bf16(a1, b1, cacc, 0, 0, 0);
        #pragma unroll
        for (int q = 0; q < 4; ++q) {
            int pk = __builtin_amdgcn_cvt_pk_fp8_f32(cacc[q] * H_SCALE, 0.f, 0, false);
            h8[(size_t)(m0 + half * 4 + q) * D + t * 16 + r] = (unsigned char)(pk & 0xff);
        }
    }
}

// ---- emb[i] = relu(base[i] + (1/S) * sum_{j in N(i)} h8[csr_col[j]]) ----
// Round-11 channel-transposed pull (16 lanes/edge, in-lane channels) with the
// edge loop widened to 4 gather slots in flight (16 edges/trip): avg deg 16
// completes in ONE trip with 4 concurrent index+gather chains.
template<int LAST>
__global__ __launch_bounds__(256) void k_pull(
        const int2* __restrict__ se_g,
        const int* __restrict__ csr_col, const unsigned char* __restrict__ h8,
        const unsigned short* __restrict__ base_bf,
        unsigned short* __restrict__ out_bf, float* __restrict__ out_f32) {
    int tid = threadIdx.x;
    int wave = tid >> 6, lane = tid & 63;
    int q = lane >> 4, l = lane & 15;   // edge slot q (0..3), channel group l: ch 4l..4l+3
    for (int it = blockIdx.x; it < NN / 4; it += gridDim.x) {
        int node = it * 4 + wave;
        int2 se = se_g[node];
        int start = se.x, end = se.y;
        float a0 = 0.f, a1 = 0.f, a2 = 0.f, a3 = 0.f;
        for (int j = start; j < end; j += 16) {     // 16 edges per trip (4 slots x 4 q)
            int e0 = j + q;
            int e1 = j + 4 + q;
            int e2 = j + 8 + q;
            int e3 = j + 12 + q;
            int c0 = (e0 < end) ? csr_col[e0] : -1;   // 16 lanes same addr: broadcast
            int c1 = (e1 < end) ? csr_col[e1] : -1;
            int c2 = (e2 < end) ? csr_col[e2] : -1;
            int c3 = (e3 < end) ? csr_col[e3] : -1;
            unsigned v0 = 0, v1 = 0, v2 = 0, v3 = 0;
            if (c0 >= 0) v0 = *((const unsigned*)(h8 + (size_t)c0 * D) + l);  // 64B/edge
            if (c1 >= 0) v1 = *((const unsigned*)(h8 + (size_t)c1 * D) + l);
            if (c2 >= 0) v2 = *((const unsigned*)(h8 + (size_t)c2 * D) + l);
            if (c3 >= 0) v3 = *((const unsigned*)(h8 + (size_t)c3 * D) + l);
            if (c0 >= 0) {
                f32x2 f0 = __builtin_amdgcn_cvt_pk_f32_fp8(v0, false);
                f32x2 f1 = __builtin_amdgcn_cvt_pk_f32_fp8(v0, true);
                a0 += f0.x; a1 += f0.y; a2 += f1.x; a3 += f1.y;
            }
            if (c1 >= 0) {
                f32x2 f0 = __builtin_amdgcn_cvt_pk_f32_fp8(v1, false);
                f32x2 f1 = __builtin_amdgcn_cvt_pk_f32_fp8(v1, true);
                a0 += f0.x; a1 += f0.y; a2 += f1.x; a3 += f1.y;
            }
            if (c2 >= 0) {
                f32x2 f0 = __builtin_amdgcn_cvt_pk_f32_fp8(v2, false);
                f32x2 f1 = __builtin_amdgcn_cvt_pk_f32_fp8(v2, true);
                a0 += f0.x; a1 += f0.y; a2 += f1.x; a3 += f1.y;
            }
            if (c3 >= 0) {
                f32x2 f0 = __builtin_amdgcn_cvt_pk_f32_fp8(v3, false);
                f32x2 f1 = __builtin_amdgcn_cvt_pk_f32_fp8(v3, true);
                a0 += f0.x; a1 += f0.y; a2 += f1.x; a3 += f1.y;
            }
        }
        // fold the 4 edge slots (lane bits 4,5): 8 shfl_xor
        a0 += __shfl_xor(a0, 16); a1 += __shfl_xor(a1, 16);
        a2 += __shfl_xor(a2, 16); a3 += __shfl_xor(a3, 16);
        a0 += __shfl_xor(a0, 32); a1 += __shfl_xor(a1, 32);
        a2 += __shfl_xor(a2, 32); a3 += __shfl_xor(a3, 32);
        if (q == 0) {   // 16 lanes: lane l covers ch 4l..4l+3 (256B contiguous store)
            ushort4v b4 = *(const ushort4v*)(base_bf + (size_t)node * D + l * 4);
            float r0 = fmaxf(fmaf(a0, H_ISCALE, bf2f(b4[0])), 0.f);
            float r1 = fmaxf(fmaf(a1, H_ISCALE, bf2f(b4[1])), 0.f);
            float r2 = fmaxf(fmaf(a2, H_ISCALE, bf2f(b4[2])), 0.f);
            float r3 = fmaxf(fmaf(a3, H_ISCALE, bf2f(b4[3])), 0.f);
            if (LAST) {
                f32x4 o4 = {r0, r1, r2, r3};
                *(f32x4*)(out_f32 + (size_t)node * D + l * 4) = o4;
            } else {
                ushort4v o4 = {f2bf(r0), f2bf(r1), f2bf(r2), f2bf(r3)};
                *(ushort4v*)(out_bf + (size_t)node * D + l * 4) = o4;
            }
        }
    }
}

extern "C" void kernel_launch(void* const* d_in, const int* in_sizes, int n_in,
                              void* d_out, int out_size, void* d_ws, size_t ws_size,
                              hipStream_t stream) {
    const float* Xv = (const float*)d_in[0];
    const int*   ei = (const int*)d_in[1];
    const float* W1 = (const float*)d_in[2];
    const float* W2 = (const float*)d_in[3];
    const float* W3 = (const float*)d_in[4];
    const float* W4 = (const float*)d_in[5];

    char* ws = (char*)d_ws;
    size_t off = 0;
    unsigned short* base_bf = (unsigned short*)(ws + off); off += (size_t)NN * D * 2; // 12.8 MB
    unsigned char* h8 = (unsigned char*)(ws + off);    off += (size_t)NN * D;      // 6.4 MB
    int* csr_col = (int*)(ws + off);                   off += (size_t)NE * 4;      // 6.4 MB
    int* cnt     = (int*)(ws + off);                   off += (size_t)NN * 4;
    int2* se_g   = (int2*)(ws + off);                  off += (size_t)NN * 8;
    int* ghist   = (int*)(ws + off);                   off += NBKT * 4;
    int* bbase   = (int*)(ws + off);                   off += (NBKT + 1) * 4;
    int* bcur    = (int*)(ws + off);                   off += NBKT * 4;
    float* cvec  = (float*)(ws + off);                 off += D * 4;
    unsigned short* w1b = (unsigned short*)(ws + off); off += D * D * 2;
    unsigned short* w2b = (unsigned short*)(ws + off); off += D * D * 2;
    unsigned* sorted = (unsigned*)(ws + off);          off += (size_t)NE * 4;      // 6.4 MB

    // intermediate bf16 emb lives in d_out's bytes (final step overwrites with fp32)
    unsigned short* emb_bf = (unsigned short*)d_out;
    float* emb_f32 = (float*)d_out;

    const int* row = ei;
    const int* col = ei + NE;

    // ---- prep (fused) + CSR build: two-level multisplit (dense writes) ----
    k_prep<<<17, 256, 0, stream>>>(W1, W2, W3, W4, w1b, w2b, cvec, ghist);
    k_hist<<<NBLK_E, 256, 0, stream>>>(row, ghist);
    k_bscan<<<1, 256, 0, stream>>>(ghist, bbase, bcur);
    k_bucket<<<NBLK_E, 256, 0, stream>>>(row, col, bcur, sorted);
    k_fine<<<NBKT, 256, 0, stream>>>(sorted, bbase, csr_col, cnt, se_g);

    // ---- base + emb1 = relu(base) + fused step-1 h ----
    k_baseh<<<(NN / 16 + 3) / 4, 256, 0, stream>>>(Xv, w1b, w2b, cnt, cvec,
                                                   base_bf, emb_bf, h8);

    // ---- 3 remaining message-passing steps (h for steps 2,3 only) ----
    for (int t = 0; t < 3; ++t) {
        if (t > 0)
            k_h<<<(NN / 16 + 3) / 4, 256, 0, stream>>>(emb_bf, w2b, h8);
        if (t < 2)
            k_pull<0><<<2048, 256, 0, stream>>>(se_g, csr_col, h8, base_bf, emb_bf, nullptr);
        else
            k_pull<1><<<2048, 256, 0, stream>>>(se_g, csr_col, h8, base_bf, nullptr, emb_f32);
    }
}

// Round 14
// 201.192 us; speedup vs baseline: 1.4105x; 1.0338x over previous
//
#include <hip/hip_runtime.h>

#define NN 100000
#define NE 1600000
#define D  64
#define BSH 8                                  // bucket shift: 256 nodes/bucket
#define NBKT ((NN + 255) >> BSH)               // 391
#define NBLK_E ((NE / 4 + 1023) / 1024)        // 391 blocks, 1024 int4s each
#define H_SCALE 256.0f
#define H_ISCALE 0.00390625f

typedef __attribute__((ext_vector_type(8))) short short8v;
typedef __attribute__((ext_vector_type(4))) unsigned short ushort4v;
typedef __attribute__((ext_vector_type(4))) float f32x4;
typedef __attribute__((ext_vector_type(2))) float f32x2;

__device__ __forceinline__ float bf2f(unsigned short x) {
    return __uint_as_float(((unsigned)x) << 16);
}
__device__ __forceinline__ unsigned short f2bf(float f) {  // RNE
    unsigned u = __float_as_uint(f);
    return (unsigned short)((u + 0x7fff + ((u >> 16) & 1)) >> 16);
}

// ---- fused prep: W1/W2 -> bf16, cvec, zero ghist ----
__global__ __launch_bounds__(256) void k_prep(
        const float* __restrict__ W1, const float* __restrict__ W2,
        const float* __restrict__ W3, const float* __restrict__ W4,
        unsigned short* __restrict__ w1b, unsigned short* __restrict__ w2b,
        float* __restrict__ cvec, int* __restrict__ ghist) {
    int b = blockIdx.x, tid = threadIdx.x;
    if (b < 16) {
        int i = b * 256 + tid;
        w1b[i] = f2bf(W1[i]);
        w2b[i] = f2bf(W2[i]);
    } else {
        for (int i = tid; i < NBKT; i += 256) ghist[i] = 0;
        if (tid < 64) {
            float s = 0.f;
            for (int k = 0; k < D; ++k) {
                float w4 = W4[k];
                s += W3[tid * D + k] * (w4 > 0.f ? w4 : 0.f);
            }
            cvec[tid] = s;
        }
    }
}

// ---- pass A: global bucket histogram (LDS-staged) ----
__global__ __launch_bounds__(256) void k_hist(const int* __restrict__ row,
                                              int* __restrict__ ghist) {
    __shared__ int h[NBKT];
    int tid = threadIdx.x;
    for (int i = tid; i < NBKT; i += 256) h[i] = 0;
    __syncthreads();
    int base4 = blockIdx.x * 1024;
    #pragma unroll
    for (int k = 0; k < 4; ++k) {
        int i4 = base4 + k * 256 + tid;
        if (i4 < NE / 4) {
            int4 r = ((const int4*)row)[i4];
            atomicAdd(&h[r.x >> BSH], 1);
            atomicAdd(&h[r.y >> BSH], 1);
            atomicAdd(&h[r.z >> BSH], 1);
            atomicAdd(&h[r.w >> BSH], 1);
        }
    }
    __syncthreads();
    for (int i = tid; i < NBKT; i += 256) if (h[i]) atomicAdd(&ghist[i], h[i]);
}

// ---- pass B: exclusive scan of 391 bucket counts (1 block) ----
__global__ __launch_bounds__(256) void k_bscan(const int* __restrict__ ghist,
                                               int* __restrict__ bbase,
                                               int* __restrict__ bcur) {
    __shared__ int sc[2][512];
    int t = threadIdx.x;
    int cur = 0;
    #pragma unroll
    for (int k = 0; k < 2; ++k) {
        int i = t + k * 256;
        sc[0][i] = (i < NBKT) ? ghist[i] : 0;
    }
    __syncthreads();
    for (int s = 1; s < 512; s <<= 1) {
        #pragma unroll
        for (int k = 0; k < 2; ++k) {
            int i = t + k * 256;
            sc[cur ^ 1][i] = sc[cur][i] + ((i >= s) ? sc[cur][i - s] : 0);
        }
        cur ^= 1;
        __syncthreads();
    }
    #pragma unroll
    for (int k = 0; k < 2; ++k) {
        int i = t + k * 256;
        if (i < NBKT) {
            int b = (i == 0) ? 0 : sc[cur][i - 1];
            bbase[i] = b;
            bcur[i] = b;
        } else if (i == NBKT) {
            bbase[NBKT] = sc[cur][NBKT - 1];   // = NE
        }
    }
}

// ---- pass C: bucket-sort edges into packed u32 (lrow<<17 | col) ----
__global__ __launch_bounds__(256) void k_bucket(const int* __restrict__ row,
                                                const int* __restrict__ col,
                                                int* __restrict__ bcur,
                                                unsigned* __restrict__ sorted) {
    __shared__ int hist[NBKT];
    __shared__ int bbase_s[NBKT];
    int tid = threadIdx.x;
    for (int i = tid; i < NBKT; i += 256) hist[i] = 0;
    __syncthreads();
    int base4 = blockIdx.x * 1024;
    int4 r4[4], c4[4];
    int rank[16];
    bool valid[4];
    #pragma unroll
    for (int k = 0; k < 4; ++k) {
        int i4 = base4 + k * 256 + tid;
        valid[k] = (i4 < NE / 4);
        if (valid[k]) {
            r4[k] = ((const int4*)row)[i4];
            c4[k] = ((const int4*)col)[i4];
            rank[k * 4 + 0] = atomicAdd(&hist[r4[k].x >> BSH], 1);
            rank[k * 4 + 1] = atomicAdd(&hist[r4[k].y >> BSH], 1);
            rank[k * 4 + 2] = atomicAdd(&hist[r4[k].z >> BSH], 1);
            rank[k * 4 + 3] = atomicAdd(&hist[r4[k].w >> BSH], 1);
        }
    }
    __syncthreads();
    for (int i = tid; i < NBKT; i += 256)
        bbase_s[i] = hist[i] ? atomicAdd(&bcur[i], hist[i]) : 0;
    __syncthreads();
    #pragma unroll
    for (int k = 0; k < 4; ++k) {
        if (valid[k]) {
            int rr[4] = {r4[k].x, r4[k].y, r4[k].z, r4[k].w};
            int cc[4] = {c4[k].x, c4[k].y, c4[k].z, c4[k].w};
            #pragma unroll
            for (int j = 0; j < 4; ++j) {
                int b = rr[j] >> BSH;
                unsigned pk = ((unsigned)(rr[j] & 255) << 17) | (unsigned)cc[j];
                sorted[bbase_s[b] + rank[k * 4 + j]] = pk;
            }
        }
    }
}

// ---- pass D: per-bucket fine CSR (LDS count -> scan -> scatter) ----
__global__ __launch_bounds__(256) void k_fine(const unsigned* __restrict__ sorted,
                                              const int* __restrict__ bbase,
                                              int* __restrict__ csr_col,
                                              int* __restrict__ cnt_g,
                                              int2* __restrict__ se_g) {
    __shared__ int cnt_s[256];
    __shared__ int cur_s[256];
    __shared__ int sc[2][256];
    int b = blockIdx.x;
    int tid = threadIdx.x;
    int s0 = bbase[b], e0 = bbase[b + 1];
    cnt_s[tid] = 0;
    __syncthreads();
    for (int i = s0 + tid; i < e0; i += 256)
        atomicAdd(&cnt_s[sorted[i] >> 17], 1);
    __syncthreads();
    int cur = 0;
    sc[0][tid] = cnt_s[tid];
    __syncthreads();
    for (int s = 1; s < 256; s <<= 1) {
        sc[cur ^ 1][tid] = sc[cur][tid] + ((tid >= s) ? sc[cur][tid - s] : 0);
        cur ^= 1;
        __syncthreads();
    }
    int incl = sc[cur][tid];
    cur_s[tid] = incl - cnt_s[tid];           // exclusive offset
    int nb = NN - b * 256;
    nb = nb > 256 ? 256 : nb;
    if (tid < nb) {
        int node = b * 256 + tid;
        cnt_g[node] = cnt_s[tid];
        se_g[node] = make_int2(s0 + incl - cnt_s[tid], s0 + incl);
    }
    __syncthreads();
    for (int i = s0 + tid; i < e0; i += 256) {
        unsigned u = sorted[i];
        int p = atomicAdd(&cur_s[u >> 17], 1);
        csr_col[s0 + p] = (int)(u & 0x1FFFFu);
    }
}

// ---- k_baseh: base_bf = bf16(Xv@W1.T + deg*c); fused step-1
//      h8 = fp8((relu(base) @ W2.T) * S) via per-wave LDS transpose ----
__global__ __launch_bounds__(256) void k_baseh(
        const float* __restrict__ Xv, const unsigned short* __restrict__ w1b,
        const unsigned short* __restrict__ w2b,
        const int* __restrict__ cnt, const float* __restrict__ cvec,
        unsigned short* __restrict__ base_bf, unsigned char* __restrict__ h8) {
    __shared__ unsigned short etile[4][16][72];   // per-wave 16x64 bf16 tile (+pad)
    int wv = threadIdx.x >> 6;
    int wid = blockIdx.x * 4 + wv;
    int lane = threadIdx.x & 63;
    int m0 = wid * 16;
    if (m0 >= NN) return;
    int r = lane & 15, half = lane >> 4;
    const float* arow = Xv + (size_t)(m0 + r) * D + half * 8;
    f32x4 xa = *(const f32x4*)(arow);
    f32x4 xb = *(const f32x4*)(arow + 4);
    f32x4 xc = *(const f32x4*)(arow + 32);
    f32x4 xd = *(const f32x4*)(arow + 36);
    short8v a0, a1;
    #pragma unroll
    for (int j = 0; j < 4; ++j) {
        a0[j]     = (short)f2bf(xa[j]);
        a0[j + 4] = (short)f2bf(xb[j]);
        a1[j]     = (short)f2bf(xc[j]);
        a1[j + 4] = (short)f2bf(xd[j]);
    }
    int4 c4 = *(const int4*)(cnt + m0 + half * 4);
    float dg[4] = {(float)c4.x, (float)c4.y, (float)c4.z, (float)c4.w};
    #pragma unroll
    for (int t = 0; t < 4; ++t) {
        short8v b0 = *(const short8v*)(w1b + (size_t)(t * 16 + r) * D + half * 8);
        short8v b1 = *(const short8v*)(w1b + (size_t)(t * 16 + r) * D + 32 + half * 8);
        f32x4 cacc = {0.f, 0.f, 0.f, 0.f};
        cacc = __builtin_amdgcn_mfma_f32_16x16x32_bf16(a0, b0, cacc, 0, 0, 0);
        cacc = __builtin_amdgcn_mfma_f32_16x16x32_bf16(a1, b1, cacc, 0, 0, 0);
        float cv = cvec[t * 16 + r];
        #pragma unroll
        for (int q = 0; q < 4; ++q) {
            float s = cacc[q] + dg[q] * cv;
            size_t idx = (size_t)(m0 + half * 4 + q) * D + t * 16 + r;
            base_bf[idx] = f2bf(s);
            etile[wv][half * 4 + q][t * 16 + r] = f2bf(s > 0.f ? s : 0.f);
        }
    }
    // fused h (step 1): A-frags from LDS tile
    short8v ha0 = *(const short8v*)(&etile[wv][r][half * 8]);
    short8v ha1 = *(const short8v*)(&etile[wv][r][32 + half * 8]);
    #pragma unroll
    for (int t = 0; t < 4; ++t) {
        short8v b0 = *(const short8v*)(w2b + (size_t)(t * 16 + r) * D + half * 8);
        short8v b1 = *(const short8v*)(w2b + (size_t)(t * 16 + r) * D + 32 + half * 8);
        f32x4 cacc = {0.f, 0.f, 0.f, 0.f};
        cacc = __builtin_amdgcn_mfma_f32_16x16x32_bf16(ha0, b0, cacc, 0, 0, 0);
        cacc = __builtin_amdgcn_mfma_f32_16x16x32_bf16(ha1, b1, cacc, 0, 0, 0);
        #pragma unroll
        for (int q = 0; q < 4; ++q) {
            int pk = __builtin_amdgcn_cvt_pk_fp8_f32(cacc[q] * H_SCALE, 0.f, 0, false);
            h8[(size_t)(m0 + half * 4 + q) * D + t * 16 + r] = (unsigned char)(pk & 0xff);
        }
    }
}

// ---- fused pull+h: one block per 16-node tile ----
// Each wave: 4 nodes sequentially (r13 gather+fold verbatim), result staged in
// LDS tile; barrier; wave w computes h-quadrant t=w of the NEXT step's h via
// MFMA into h_out (ping-pong). LAST: write fp32 emb to d_out, no h.
template<int LAST>
__global__ __launch_bounds__(256) void k_pullh(
        const int2* __restrict__ se_g,
        const int* __restrict__ csr_col, const unsigned char* __restrict__ h_in,
        const unsigned short* __restrict__ base_bf,
        const unsigned short* __restrict__ w2b,
        unsigned char* __restrict__ h_out, float* __restrict__ out_f32) {
    __shared__ unsigned short etile[16][72];
    int tid = threadIdx.x;
    int wv = tid >> 6, lane = tid & 63;
    int q = lane >> 4, l = lane & 15;   // edge slot q (0..3), channel group l
    int m0 = blockIdx.x * 16;           // 6250 blocks, NN%16==0
    #pragma unroll
    for (int s = 0; s < 4; ++s) {
        int node = m0 + wv * 4 + s;
        int2 se = se_g[node];
        int start = se.x, end = se.y;
        float a0 = 0.f, a1 = 0.f, a2 = 0.f, a3 = 0.f;
        for (int j = start; j < end; j += 16) {     // 16 edges/trip (4 slots x 4 q)
            int e0 = j + q;
            int e1 = j + 4 + q;
            int e2 = j + 8 + q;
            int e3 = j + 12 + q;
            int c0 = (e0 < end) ? csr_col[e0] : -1;
            int c1 = (e1 < end) ? csr_col[e1] : -1;
            int c2 = (e2 < end) ? csr_col[e2] : -1;
            int c3 = (e3 < end) ? csr_col[e3] : -1;
            unsigned v0 = 0, v1 = 0, v2 = 0, v3 = 0;
            if (c0 >= 0) v0 = *((const unsigned*)(h_in + (size_t)c0 * D) + l);
            if (c1 >= 0) v1 = *((const unsigned*)(h_in + (size_t)c1 * D) + l);
            if (c2 >= 0) v2 = *((const unsigned*)(h_in + (size_t)c2 * D) + l);
            if (c3 >= 0) v3 = *((const unsigned*)(h_in + (size_t)c3 * D) + l);
            if (c0 >= 0) {
                f32x2 f0 = __builtin_amdgcn_cvt_pk_f32_fp8(v0, false);
                f32x2 f1 = __builtin_amdgcn_cvt_pk_f32_fp8(v0, true);
                a0 += f0.x; a1 += f0.y; a2 += f1.x; a3 += f1.y;
            }
            if (c1 >= 0) {
                f32x2 f0 = __builtin_amdgcn_cvt_pk_f32_fp8(v1, false);
                f32x2 f1 = __builtin_amdgcn_cvt_pk_f32_fp8(v1, true);
                a0 += f0.x; a1 += f0.y; a2 += f1.x; a3 += f1.y;
            }
            if (c2 >= 0) {
                f32x2 f0 = __builtin_amdgcn_cvt_pk_f32_fp8(v2, false);
                f32x2 f1 = __builtin_amdgcn_cvt_pk_f32_fp8(v2, true);
                a0 += f0.x; a1 += f0.y; a2 += f1.x; a3 += f1.y;
            }
            if (c3 >= 0) {
                f32x2 f0 = __builtin_amdgcn_cvt_pk_f32_fp8(v3, false);
                f32x2 f1 = __builtin_amdgcn_cvt_pk_f32_fp8(v3, true);
                a0 += f0.x; a1 += f0.y; a2 += f1.x; a3 += f1.y;
            }
        }
        // fold the 4 edge slots (lane bits 4,5)
        a0 += __shfl_xor(a0, 16); a1 += __shfl_xor(a1, 16);
        a2 += __shfl_xor(a2, 16); a3 += __shfl_xor(a3, 16);
        a0 += __shfl_xor(a0, 32); a1 += __shfl_xor(a1, 32);
        a2 += __shfl_xor(a2, 32); a3 += __shfl_xor(a3, 32);
        ushort4v b4 = *(const ushort4v*)(base_bf + (size_t)node * D + l * 4);
        float r0 = fmaxf(fmaf(a0, H_ISCALE, bf2f(b4[0])), 0.f);
        float r1 = fmaxf(fmaf(a1, H_ISCALE, bf2f(b4[1])), 0.f);
        float r2 = fmaxf(fmaf(a2, H_ISCALE, bf2f(b4[2])), 0.f);
        float r3 = fmaxf(fmaf(a3, H_ISCALE, bf2f(b4[3])), 0.f);
        if (LAST) {
            if (q == 0) {
                f32x4 o4 = {r0, r1, r2, r3};
                *(f32x4*)(out_f32 + (size_t)node * D + l * 4) = o4;
            }
        } else {
            if (q == 0) {
                ushort4v o4 = {f2bf(r0), f2bf(r1), f2bf(r2), f2bf(r3)};
                *(ushort4v*)(&etile[wv * 4 + s][l * 4]) = o4;
            }
        }
    }
    if (!LAST) {
        __syncthreads();
        // wave wv computes h-quadrant t = wv for the 16-node tile
        int r = lane & 15, half = lane >> 4;
        short8v ha0 = *(const short8v*)(&etile[r][half * 8]);
        short8v ha1 = *(const short8v*)(&etile[r][32 + half * 8]);
        int t = wv;
        short8v b0 = *(const short8v*)(w2b + (size_t)(t * 16 + r) * D + half * 8);
        short8v b1 = *(const short8v*)(w2b + (size_t)(t * 16 + r) * D + 32 + half * 8);
        f32x4 cacc = {0.f, 0.f, 0.f, 0.f};
        cacc = __builtin_amdgcn_mfma_f32_16x16x32_bf16(ha0, b0, cacc, 0, 0, 0);
        cacc = __builtin_amdgcn_mfma_f32_16x16x32_bf16(ha1, b1, cacc, 0, 0, 0);
        #pragma unroll
        for (int qq = 0; qq < 4; ++qq) {
            int pk = __builtin_amdgcn_cvt_pk_fp8_f32(cacc[qq] * H_SCALE, 0.f, 0, false);
            h_out[(size_t)(m0 + half * 4 + qq) * D + t * 16 + r] = (unsigned char)(pk & 0xff);
        }
    }
}

extern "C" void kernel_launch(void* const* d_in, const int* in_sizes, int n_in,
                              void* d_out, int out_size, void* d_ws, size_t ws_size,
                              hipStream_t stream) {
    const float* Xv = (const float*)d_in[0];
    const int*   ei = (const int*)d_in[1];
    const float* W1 = (const float*)d_in[2];
    const float* W2 = (const float*)d_in[3];
    const float* W3 = (const float*)d_in[4];
    const float* W4 = (const float*)d_in[5];

    char* ws = (char*)d_ws;
    size_t off = 0;
    unsigned short* base_bf = (unsigned short*)(ws + off); off += (size_t)NN * D * 2; // 12.8 MB
    unsigned char* h8a = (unsigned char*)(ws + off);   off += (size_t)NN * D;      // 6.4 MB
    unsigned char* h8b = (unsigned char*)(ws + off);   off += (size_t)NN * D;      // 6.4 MB
    int* csr_col = (int*)(ws + off);                   off += (size_t)NE * 4;      // 6.4 MB
    int* cnt     = (int*)(ws + off);                   off += (size_t)NN * 4;
    int2* se_g   = (int2*)(ws + off);                  off += (size_t)NN * 8;
    int* ghist   = (int*)(ws + off);                   off += NBKT * 4;
    int* bbase   = (int*)(ws + off);                   off += (NBKT + 1) * 4;
    int* bcur    = (int*)(ws + off);                   off += NBKT * 4;
    float* cvec  = (float*)(ws + off);                 off += D * 4;
    unsigned short* w1b = (unsigned short*)(ws + off); off += D * D * 2;
    unsigned short* w2b = (unsigned short*)(ws + off); off += D * D * 2;
    unsigned* sorted = (unsigned*)(ws + off);          off += (size_t)NE * 4;      // 6.4 MB

    float* emb_f32 = (float*)d_out;

    const int* row = ei;
    const int* col = ei + NE;

    // ---- prep (fused) + CSR build: two-level multisplit (dense writes) ----
    k_prep<<<17, 256, 0, stream>>>(W1, W2, W3, W4, w1b, w2b, cvec, ghist);
    k_hist<<<NBLK_E, 256, 0, stream>>>(row, ghist);
    k_bscan<<<1, 256, 0, stream>>>(ghist, bbase, bcur);
    k_bucket<<<NBLK_E, 256, 0, stream>>>(row, col, bcur, sorted);
    k_fine<<<NBKT, 256, 0, stream>>>(sorted, bbase, csr_col, cnt, se_g);

    // ---- base + fused step-1 h ----
    k_baseh<<<(NN / 16 + 3) / 4, 256, 0, stream>>>(Xv, w1b, w2b, cnt, cvec,
                                                   base_bf, h8a);

    // ---- 3 message-passing steps, h fused into pull (ping-pong h buffers) ----
    k_pullh<0><<<NN / 16, 256, 0, stream>>>(se_g, csr_col, h8a, base_bf, w2b, h8b, nullptr);
    k_pullh<0><<<NN / 16, 256, 0, stream>>>(se_g, csr_col, h8b, base_bf, w2b, h8a, nullptr);
    k_pullh<1><<<NN / 16, 256, 0, stream>>>(se_g, csr_col, h8a, base_bf, w2b, nullptr, emb_f32);
}

// Round 15
// 193.318 us; speedup vs baseline: 1.4679x; 1.0407x over previous
//
#include <hip/hip_runtime.h>

#define NN 100000
#define NE 1600000
#define D  64
#define BSH 8                                  // bucket shift: 256 nodes/bucket
#define NBKT ((NN + 255) >> BSH)               // 391
#define NBLK_E ((NE / 4 + 1023) / 1024)        // 391 blocks, 1024 int4s each
#define H_SCALE 256.0f
#define H_ISCALE 0.00390625f

typedef __attribute__((ext_vector_type(8))) short short8v;
typedef __attribute__((ext_vector_type(4))) unsigned short ushort4v;
typedef __attribute__((ext_vector_type(4))) float f32x4;
typedef __attribute__((ext_vector_type(2))) float f32x2;

__device__ __forceinline__ float bf2f(unsigned short x) {
    return __uint_as_float(((unsigned)x) << 16);
}
__device__ __forceinline__ unsigned short f2bf(float f) {  // RNE
    unsigned u = __float_as_uint(f);
    return (unsigned short)((u + 0x7fff + ((u >> 16) & 1)) >> 16);
}

// ---- fused prep: W1/W2 -> bf16, cvec, zero ghist ----
__global__ __launch_bounds__(256) void k_prep(
        const float* __restrict__ W1, const float* __restrict__ W2,
        const float* __restrict__ W3, const float* __restrict__ W4,
        unsigned short* __restrict__ w1b, unsigned short* __restrict__ w2b,
        float* __restrict__ cvec, int* __restrict__ ghist) {
    int b = blockIdx.x, tid = threadIdx.x;
    if (b < 16) {
        int i = b * 256 + tid;
        w1b[i] = f2bf(W1[i]);
        w2b[i] = f2bf(W2[i]);
    } else {
        for (int i = tid; i < NBKT; i += 256) ghist[i] = 0;
        if (tid < 64) {
            float s = 0.f;
            for (int k = 0; k < D; ++k) {
                float w4 = W4[k];
                s += W3[tid * D + k] * (w4 > 0.f ? w4 : 0.f);
            }
            cvec[tid] = s;
        }
    }
}

// ---- pass A: global bucket histogram (LDS-staged) ----
__global__ __launch_bounds__(256) void k_hist(const int* __restrict__ row,
                                              int* __restrict__ ghist) {
    __shared__ int h[NBKT];
    int tid = threadIdx.x;
    for (int i = tid; i < NBKT; i += 256) h[i] = 0;
    __syncthreads();
    int base4 = blockIdx.x * 1024;
    #pragma unroll
    for (int k = 0; k < 4; ++k) {
        int i4 = base4 + k * 256 + tid;
        if (i4 < NE / 4) {
            int4 r = ((const int4*)row)[i4];
            atomicAdd(&h[r.x >> BSH], 1);
            atomicAdd(&h[r.y >> BSH], 1);
            atomicAdd(&h[r.z >> BSH], 1);
            atomicAdd(&h[r.w >> BSH], 1);
        }
    }
    __syncthreads();
    for (int i = tid; i < NBKT; i += 256) if (h[i]) atomicAdd(&ghist[i], h[i]);
}

// ---- pass B: exclusive scan of 391 bucket counts (1 block) ----
__global__ __launch_bounds__(256) void k_bscan(const int* __restrict__ ghist,
                                               int* __restrict__ bbase,
                                               int* __restrict__ bcur) {
    __shared__ int sc[2][512];
    int t = threadIdx.x;
    int cur = 0;
    #pragma unroll
    for (int k = 0; k < 2; ++k) {
        int i = t + k * 256;
        sc[0][i] = (i < NBKT) ? ghist[i] : 0;
    }
    __syncthreads();
    for (int s = 1; s < 512; s <<= 1) {
        #pragma unroll
        for (int k = 0; k < 2; ++k) {
            int i = t + k * 256;
            sc[cur ^ 1][i] = sc[cur][i] + ((i >= s) ? sc[cur][i - s] : 0);
        }
        cur ^= 1;
        __syncthreads();
    }
    #pragma unroll
    for (int k = 0; k < 2; ++k) {
        int i = t + k * 256;
        if (i < NBKT) {
            int b = (i == 0) ? 0 : sc[cur][i - 1];
            bbase[i] = b;
            bcur[i] = b;
        } else if (i == NBKT) {
            bbase[NBKT] = sc[cur][NBKT - 1];   // = NE
        }
    }
}

// ---- pass C: bucket-sort edges into packed u32 (lrow<<17 | col) ----
__global__ __launch_bounds__(256) void k_bucket(const int* __restrict__ row,
                                                const int* __restrict__ col,
                                                int* __restrict__ bcur,
                                                unsigned* __restrict__ sorted) {
    __shared__ int hist[NBKT];
    __shared__ int bbase_s[NBKT];
    int tid = threadIdx.x;
    for (int i = tid; i < NBKT; i += 256) hist[i] = 0;
    __syncthreads();
    int base4 = blockIdx.x * 1024;
    int4 r4[4], c4[4];
    int rank[16];
    bool valid[4];
    #pragma unroll
    for (int k = 0; k < 4; ++k) {
        int i4 = base4 + k * 256 + tid;
        valid[k] = (i4 < NE / 4);
        if (valid[k]) {
            r4[k] = ((const int4*)row)[i4];
            c4[k] = ((const int4*)col)[i4];
            rank[k * 4 + 0] = atomicAdd(&hist[r4[k].x >> BSH], 1);
            rank[k * 4 + 1] = atomicAdd(&hist[r4[k].y >> BSH], 1);
            rank[k * 4 + 2] = atomicAdd(&hist[r4[k].z >> BSH], 1);
            rank[k * 4 + 3] = atomicAdd(&hist[r4[k].w >> BSH], 1);
        }
    }
    __syncthreads();
    for (int i = tid; i < NBKT; i += 256)
        bbase_s[i] = hist[i] ? atomicAdd(&bcur[i], hist[i]) : 0;
    __syncthreads();
    #pragma unroll
    for (int k = 0; k < 4; ++k) {
        if (valid[k]) {
            int rr[4] = {r4[k].x, r4[k].y, r4[k].z, r4[k].w};
            int cc[4] = {c4[k].x, c4[k].y, c4[k].z, c4[k].w};
            #pragma unroll
            for (int j = 0; j < 4; ++j) {
                int b = rr[j] >> BSH;
                unsigned pk = ((unsigned)(rr[j] & 255) << 17) | (unsigned)cc[j];
                sorted[bbase_s[b] + rank[k * 4 + j]] = pk;
            }
        }
    }
}

// ---- pass D: per-bucket fine CSR with 16B-ALIGNED per-node starts ----
// Node starts padded to multiples of 4 entries; gaps never read. Bucket base
// pbase(b) = align4(bbase[b]) + 768*b  (768 = 3*256 worst-case pad per bucket).
__global__ __launch_bounds__(256) void k_fine(const unsigned* __restrict__ sorted,
                                              const int* __restrict__ bbase,
                                              int* __restrict__ csr_col,
                                              int* __restrict__ cnt_g,
                                              int2* __restrict__ se_g) {
    __shared__ int cnt_s[256];
    __shared__ int cur_s[256];
    __shared__ int sc[2][256];
    int b = blockIdx.x;
    int tid = threadIdx.x;
    int s0 = bbase[b], e0 = bbase[b + 1];
    int pbase = ((s0 + 3) & ~3) + 768 * b;
    cnt_s[tid] = 0;
    __syncthreads();
    for (int i = s0 + tid; i < e0; i += 256)
        atomicAdd(&cnt_s[sorted[i] >> 17], 1);
    __syncthreads();
    int cnt = cnt_s[tid];
    int pc = (cnt + 3) & ~3;            // padded count (4-entry multiple)
    int cur = 0;
    sc[0][tid] = pc;
    __syncthreads();
    for (int s = 1; s < 256; s <<= 1) {
        sc[cur ^ 1][tid] = sc[cur][tid] + ((tid >= s) ? sc[cur][tid - s] : 0);
        cur ^= 1;
        __syncthreads();
    }
    int incl = sc[cur][tid];
    int excl = incl - pc;               // padded exclusive offset within bucket
    cur_s[tid] = excl;
    int nb = NN - b * 256;
    nb = nb > 256 ? 256 : nb;
    if (tid < nb) {
        int node = b * 256 + tid;
        cnt_g[node] = cnt;
        se_g[node] = make_int2(pbase + excl, pbase + excl + cnt);
    }
    __syncthreads();
    for (int i = s0 + tid; i < e0; i += 256) {
        unsigned u = sorted[i];
        int p = atomicAdd(&cur_s[u >> 17], 1);
        csr_col[pbase + p] = (int)(u & 0x1FFFFu);
    }
}

// ---- k_baseh: base_bf = bf16(Xv@W1.T + deg*c); fused step-1
//      h8 = fp8((relu(base) @ W2.T) * S) via per-wave LDS transpose ----
__global__ __launch_bounds__(256) void k_baseh(
        const float* __restrict__ Xv, const unsigned short* __restrict__ w1b,
        const unsigned short* __restrict__ w2b,
        const int* __restrict__ cnt, const float* __restrict__ cvec,
        unsigned short* __restrict__ base_bf, unsigned char* __restrict__ h8) {
    __shared__ unsigned short etile[4][16][72];   // per-wave 16x64 bf16 tile (+pad)
    int wv = threadIdx.x >> 6;
    int wid = blockIdx.x * 4 + wv;
    int lane = threadIdx.x & 63;
    int m0 = wid * 16;
    if (m0 >= NN) return;
    int r = lane & 15, half = lane >> 4;
    const float* arow = Xv + (size_t)(m0 + r) * D + half * 8;
    f32x4 xa = *(const f32x4*)(arow);
    f32x4 xb = *(const f32x4*)(arow + 4);
    f32x4 xc = *(const f32x4*)(arow + 32);
    f32x4 xd = *(const f32x4*)(arow + 36);
    short8v a0, a1;
    #pragma unroll
    for (int j = 0; j < 4; ++j) {
        a0[j]     = (short)f2bf(xa[j]);
        a0[j + 4] = (short)f2bf(xb[j]);
        a1[j]     = (short)f2bf(xc[j]);
        a1[j + 4] = (short)f2bf(xd[j]);
    }
    int4 c4 = *(const int4*)(cnt + m0 + half * 4);
    float dg[4] = {(float)c4.x, (float)c4.y, (float)c4.z, (float)c4.w};
    #pragma unroll
    for (int t = 0; t < 4; ++t) {
        short8v b0 = *(const short8v*)(w1b + (size_t)(t * 16 + r) * D + half * 8);
        short8v b1 = *(const short8v*)(w1b + (size_t)(t * 16 + r) * D + 32 + half * 8);
        f32x4 cacc = {0.f, 0.f, 0.f, 0.f};
        cacc = __builtin_amdgcn_mfma_f32_16x16x32_bf16(a0, b0, cacc, 0, 0, 0);
        cacc = __builtin_amdgcn_mfma_f32_16x16x32_bf16(a1, b1, cacc, 0, 0, 0);
        float cv = cvec[t * 16 + r];
        #pragma unroll
        for (int q = 0; q < 4; ++q) {
            float s = cacc[q] + dg[q] * cv;
            size_t idx = (size_t)(m0 + half * 4 + q) * D + t * 16 + r;
            base_bf[idx] = f2bf(s);
            etile[wv][half * 4 + q][t * 16 + r] = f2bf(s > 0.f ? s : 0.f);
        }
    }
    // fused h (step 1): A-frags from LDS tile
    short8v ha0 = *(const short8v*)(&etile[wv][r][half * 8]);
    short8v ha1 = *(const short8v*)(&etile[wv][r][32 + half * 8]);
    #pragma unroll
    for (int t = 0; t < 4; ++t) {
        short8v b0 = *(const short8v*)(w2b + (size_t)(t * 16 + r) * D + half * 8);
        short8v b1 = *(const short8v*)(w2b + (size_t)(t * 16 + r) * D + 32 + half * 8);
        f32x4 cacc = {0.f, 0.f, 0.f, 0.f};
        cacc = __builtin_amdgcn_mfma_f32_16x16x32_bf16(ha0, b0, cacc, 0, 0, 0);
        cacc = __builtin_amdgcn_mfma_f32_16x16x32_bf16(ha1, b1, cacc, 0, 0, 0);
        #pragma unroll
        for (int q = 0; q < 4; ++q) {
            int pk = __builtin_amdgcn_cvt_pk_fp8_f32(cacc[q] * H_SCALE, 0.f, 0, false);
            h8[(size_t)(m0 + half * 4 + q) * D + t * 16 + r] = (unsigned char)(pk & 0xff);
        }
    }
}

// ---- fused pull+h: one block per 16-node tile ----
// Full 16-edge trips: one broadcast int4 index load (aligned via padded CSR),
// 4 unconditional gathers, no compares. Checked tail handles <16 remainder.
template<int LAST>
__global__ __launch_bounds__(256) void k_pullh(
        const int2* __restrict__ se_g,
        const int* __restrict__ csr_col, const unsigned char* __restrict__ h_in,
        const unsigned short* __restrict__ base_bf,
        const unsigned short* __restrict__ w2b,
        unsigned char* __restrict__ h_out, float* __restrict__ out_f32) {
    __shared__ unsigned short etile[16][72];
    int tid = threadIdx.x;
    int wv = tid >> 6, lane = tid & 63;
    int q = lane >> 4, l = lane & 15;   // edge slot q (0..3), channel group l
    int m0 = blockIdx.x * 16;           // 6250 blocks, NN%16==0
    #pragma unroll
    for (int s = 0; s < 4; ++s) {
        int node = m0 + wv * 4 + s;
        int2 se = se_g[node];
        int start = se.x, end = se.y;
        float a0 = 0.f, a1 = 0.f, a2 = 0.f, a3 = 0.f;
        int j = start;
        for (; j + 16 <= end; j += 16) {   // fast path: slot q owns edges j+4q..j+4q+3
            int4 c = *(const int4*)(csr_col + j + 4 * q);   // 16B-aligned broadcast
            unsigned v0 = *((const unsigned*)(h_in + (size_t)c.x * D) + l);
            unsigned v1 = *((const unsigned*)(h_in + (size_t)c.y * D) + l);
            unsigned v2 = *((const unsigned*)(h_in + (size_t)c.z * D) + l);
            unsigned v3 = *((const unsigned*)(h_in + (size_t)c.w * D) + l);
            f32x2 f;
            f = __builtin_amdgcn_cvt_pk_f32_fp8(v0, false); a0 += f.x; a1 += f.y;
            f = __builtin_amdgcn_cvt_pk_f32_fp8(v0, true);  a2 += f.x; a3 += f.y;
            f = __builtin_amdgcn_cvt_pk_f32_fp8(v1, false); a0 += f.x; a1 += f.y;
            f = __builtin_amdgcn_cvt_pk_f32_fp8(v1, true);  a2 += f.x; a3 += f.y;
            f = __builtin_amdgcn_cvt_pk_f32_fp8(v2, false); a0 += f.x; a1 += f.y;
            f = __builtin_amdgcn_cvt_pk_f32_fp8(v2, true);  a2 += f.x; a3 += f.y;
            f = __builtin_amdgcn_cvt_pk_f32_fp8(v3, false); a0 += f.x; a1 += f.y;
            f = __builtin_amdgcn_cvt_pk_f32_fp8(v3, true);  a2 += f.x; a3 += f.y;
        }
        if (j < end) {                     // checked tail (<16 edges)
            int e0 = j + q;
            int e1 = j + 4 + q;
            int e2 = j + 8 + q;
            int e3 = j + 12 + q;
            int c0 = (e0 < end) ? csr_col[e0] : -1;
            int c1 = (e1 < end) ? csr_col[e1] : -1;
            int c2 = (e2 < end) ? csr_col[e2] : -1;
            int c3 = (e3 < end) ? csr_col[e3] : -1;
            unsigned v0 = 0, v1 = 0, v2 = 0, v3 = 0;
            if (c0 >= 0) v0 = *((const unsigned*)(h_in + (size_t)c0 * D) + l);
            if (c1 >= 0) v1 = *((const unsigned*)(h_in + (size_t)c1 * D) + l);
            if (c2 >= 0) v2 = *((const unsigned*)(h_in + (size_t)c2 * D) + l);
            if (c3 >= 0) v3 = *((const unsigned*)(h_in + (size_t)c3 * D) + l);
            f32x2 f;
            if (c0 >= 0) {
                f = __builtin_amdgcn_cvt_pk_f32_fp8(v0, false); a0 += f.x; a1 += f.y;
                f = __builtin_amdgcn_cvt_pk_f32_fp8(v0, true);  a2 += f.x; a3 += f.y;
            }
            if (c1 >= 0) {
                f = __builtin_amdgcn_cvt_pk_f32_fp8(v1, false); a0 += f.x; a1 += f.y;
                f = __builtin_amdgcn_cvt_pk_f32_fp8(v1, true);  a2 += f.x; a3 += f.y;
            }
            if (c2 >= 0) {
                f = __builtin_amdgcn_cvt_pk_f32_fp8(v2, false); a0 += f.x; a1 += f.y;
                f = __builtin_amdgcn_cvt_pk_f32_fp8(v2, true);  a2 += f.x; a3 += f.y;
            }
            if (c3 >= 0) {
                f = __builtin_amdgcn_cvt_pk_f32_fp8(v3, false); a0 += f.x; a1 += f.y;
                f = __builtin_amdgcn_cvt_pk_f32_fp8(v3, true);  a2 += f.x; a3 += f.y;
            }
        }
        // fold the 4 edge slots (lane bits 4,5)
        a0 += __shfl_xor(a0, 16); a1 += __shfl_xor(a1, 16);
        a2 += __shfl_xor(a2, 16); a3 += __shfl_xor(a3, 16);
        a0 += __shfl_xor(a0, 32); a1 += __shfl_xor(a1, 32);
        a2 += __shfl_xor(a2, 32); a3 += __shfl_xor(a3, 32);
        if (q == 0) {
            ushort4v b4 = *(const ushort4v*)(base_bf + (size_t)node * D + l * 4);
            float r0 = fmaxf(fmaf(a0, H_ISCALE, bf2f(b4[0])), 0.f);
            float r1 = fmaxf(fmaf(a1, H_ISCALE, bf2f(b4[1])), 0.f);
            float r2 = fmaxf(fmaf(a2, H_ISCALE, bf2f(b4[2])), 0.f);
            float r3 = fmaxf(fmaf(a3, H_ISCALE, bf2f(b4[3])), 0.f);
            if (LAST) {
                f32x4 o4 = {r0, r1, r2, r3};
                *(f32x4*)(out_f32 + (size_t)node * D + l * 4) = o4;
            } else {
                ushort4v o4 = {f2bf(r0), f2bf(r1), f2bf(r2), f2bf(r3)};
                *(ushort4v*)(&etile[wv * 4 + s][l * 4]) = o4;
            }
        }
    }
    if (!LAST) {
        __syncthreads();
        // wave wv computes h-quadrant t = wv for the 16-node tile
        int r = lane & 15, half = lane >> 4;
        short8v ha0 = *(const short8v*)(&etile[r][half * 8]);
        short8v ha1 = *(const short8v*)(&etile[r][32 + half * 8]);
        int t = wv;
        short8v b0 = *(const short8v*)(w2b + (size_t)(t * 16 + r) * D + half * 8);
        short8v b1 = *(const short8v*)(w2b + (size_t)(t * 16 + r) * D + 32 + half * 8);
        f32x4 cacc = {0.f, 0.f, 0.f, 0.f};
        cacc = __builtin_amdgcn_mfma_f32_16x16x32_bf16(ha0, b0, cacc, 0, 0, 0);
        cacc = __builtin_amdgcn_mfma_f32_16x16x32_bf16(ha1, b1, cacc, 0, 0, 0);
        #pragma unroll
        for (int qq = 0; qq < 4; ++qq) {
            int pk = __builtin_amdgcn_cvt_pk_fp8_f32(cacc[qq] * H_SCALE, 0.f, 0, false);
            h_out[(size_t)(m0 + half * 4 + qq) * D + t * 16 + r] = (unsigned char)(pk & 0xff);
        }
    }
}

extern "C" void kernel_launch(void* const* d_in, const int* in_sizes, int n_in,
                              void* d_out, int out_size, void* d_ws, size_t ws_size,
                              hipStream_t stream) {
    const float* Xv = (const float*)d_in[0];
    const int*   ei = (const int*)d_in[1];
    const float* W1 = (const float*)d_in[2];
    const float* W2 = (const float*)d_in[3];
    const float* W3 = (const float*)d_in[4];
    const float* W4 = (const float*)d_in[5];

    char* ws = (char*)d_ws;
    size_t off = 0;
    unsigned short* base_bf = (unsigned short*)(ws + off); off += (size_t)NN * D * 2; // 12.8 MB
    unsigned char* h8a = (unsigned char*)(ws + off);   off += (size_t)NN * D;      // 6.4 MB
    unsigned char* h8b = (unsigned char*)(ws + off);   off += (size_t)NN * D;      // 6.4 MB
    int* csr_col = (int*)(ws + off);                   off += ((size_t)NE + 768 * NBKT + 16) * 4; // 7.6 MB (padded)
    int* cnt     = (int*)(ws + off);                   off += (size_t)NN * 4;
    int2* se_g   = (int2*)(ws + off);                  off += (size_t)NN * 8;
    int* ghist   = (int*)(ws + off);                   off += NBKT * 4;
    int* bbase   = (int*)(ws + off);                   off += (NBKT + 1) * 4;
    int* bcur    = (int*)(ws + off);                   off += NBKT * 4;
    float* cvec  = (float*)(ws + off);                 off += D * 4;
    unsigned short* w1b = (unsigned short*)(ws + off); off += D * D * 2;
    unsigned short* w2b = (unsigned short*)(ws + off); off += D * D * 2;
    off = (off + 15) & ~(size_t)15;
    unsigned* sorted = (unsigned*)(ws + off);          off += (size_t)NE * 4;      // 6.4 MB

    float* emb_f32 = (float*)d_out;

    const int* row = ei;
    const int* col = ei + NE;

    // ---- prep (fused) + CSR build: two-level multisplit (dense writes) ----
    k_prep<<<17, 256, 0, stream>>>(W1, W2, W3, W4, w1b, w2b, cvec, ghist);
    k_hist<<<NBLK_E, 256, 0, stream>>>(row, ghist);
    k_bscan<<<1, 256, 0, stream>>>(ghist, bbase, bcur);
    k_bucket<<<NBLK_E, 256, 0, stream>>>(row, col, bcur, sorted);
    k_fine<<<NBKT, 256, 0, stream>>>(sorted, bbase, csr_col, cnt, se_g);

    // ---- base + fused step-1 h ----
    k_baseh<<<(NN / 16 + 3) / 4, 256, 0, stream>>>(Xv, w1b, w2b, cnt, cvec,
                                                   base_bf, h8a);

    // ---- 3 message-passing steps, h fused into pull (ping-pong h buffers) ----
    k_pullh<0><<<NN / 16, 256, 0, stream>>>(se_g, csr_col, h8a, base_bf, w2b, h8b, nullptr);
    k_pullh<0><<<NN / 16, 256, 0, stream>>>(se_g, csr_col, h8b, base_bf, w2b, h8a, nullptr);
    k_pullh<1><<<NN / 16, 256, 0, stream>>>(se_g, csr_col, h8a, base_bf, w2b, nullptr, emb_f32);
}

// Round 16
// 178.437 us; speedup vs baseline: 1.5903x; 1.0834x over previous
//
#include <hip/hip_runtime.h>

#define NN 100000
#define NE 1600000
#define D  64
#define BSH 8                                  // bucket shift: 256 nodes/bucket
#define NBKT ((NN + 255) >> BSH)               // 391
#define NBLK_E ((NE / 4 + 1023) / 1024)        // 391 blocks, 1024 int4s each
#define SCAP 4608                              // sorted capacity/bucket (mean 4096 + 8 sigma)
#define CCAP 8448                              // csr capacity/bucket (4608 + 15*256 pad)
#define H_SCALE 256.0f
#define H_ISCALE 0.00390625f

typedef __attribute__((ext_vector_type(8))) short short8v;
typedef __attribute__((ext_vector_type(4))) unsigned short ushort4v;
typedef __attribute__((ext_vector_type(4))) float f32x4;
typedef __attribute__((ext_vector_type(2))) float f32x2;

__device__ __forceinline__ float bf2f(unsigned short x) {
    return __uint_as_float(((unsigned)x) << 16);
}
__device__ __forceinline__ unsigned short f2bf(float f) {  // RNE
    unsigned u = __float_as_uint(f);
    return (unsigned short)((u + 0x7fff + ((u >> 16) & 1)) >> 16);
}

// ---- fused prep: W1/W2 -> bf16, cvec, zero bcur, zero h sentinel rows ----
__global__ __launch_bounds__(256) void k_prep(
        const float* __restrict__ W1, const float* __restrict__ W2,
        const float* __restrict__ W3, const float* __restrict__ W4,
        unsigned short* __restrict__ w1b, unsigned short* __restrict__ w2b,
        float* __restrict__ cvec, int* __restrict__ bcur,
        unsigned char* __restrict__ h8a, unsigned char* __restrict__ h8b) {
    int b = blockIdx.x, tid = threadIdx.x;
    if (b < 16) {
        int i = b * 256 + tid;
        w1b[i] = f2bf(W1[i]);
        w2b[i] = f2bf(W2[i]);
    } else {
        for (int i = tid; i < NBKT; i += 256) bcur[i] = 0;
        if (tid < 16) ((unsigned*)(h8a + (size_t)NN * D))[tid] = 0;   // sentinel row = 0
        else if (tid < 32) ((unsigned*)(h8b + (size_t)NN * D))[tid - 16] = 0;
        if (tid < 64) {
            float s = 0.f;
            for (int k = 0; k < D; ++k) {
                float w4 = W4[k];
                s += W3[tid * D + k] * (w4 > 0.f ? w4 : 0.f);
            }
            cvec[tid] = s;
        }
    }
}

// ---- bucket-sort edges into fixed-capacity regions: sorted[b*SCAP + pos] ----
__global__ __launch_bounds__(256) void k_bucket(const int* __restrict__ row,
                                                const int* __restrict__ col,
                                                int* __restrict__ bcur,
                                                unsigned* __restrict__ sorted) {
    __shared__ int hist[NBKT];
    __shared__ int bbase_s[NBKT];
    int tid = threadIdx.x;
    for (int i = tid; i < NBKT; i += 256) hist[i] = 0;
    __syncthreads();
    int base4 = blockIdx.x * 1024;
    int4 r4[4], c4[4];
    int rank[16];
    bool valid[4];
    #pragma unroll
    for (int k = 0; k < 4; ++k) {
        int i4 = base4 + k * 256 + tid;
        valid[k] = (i4 < NE / 4);
        if (valid[k]) {
            r4[k] = ((const int4*)row)[i4];
            c4[k] = ((const int4*)col)[i4];
            rank[k * 4 + 0] = atomicAdd(&hist[r4[k].x >> BSH], 1);
            rank[k * 4 + 1] = atomicAdd(&hist[r4[k].y >> BSH], 1);
            rank[k * 4 + 2] = atomicAdd(&hist[r4[k].z >> BSH], 1);
            rank[k * 4 + 3] = atomicAdd(&hist[r4[k].w >> BSH], 1);
        }
    }
    __syncthreads();
    for (int i = tid; i < NBKT; i += 256)
        bbase_s[i] = hist[i] ? atomicAdd(&bcur[i], hist[i]) : 0;
    __syncthreads();
    #pragma unroll
    for (int k = 0; k < 4; ++k) {
        if (valid[k]) {
            int rr[4] = {r4[k].x, r4[k].y, r4[k].z, r4[k].w};
            int cc[4] = {c4[k].x, c4[k].y, c4[k].z, c4[k].w};
            #pragma unroll
            for (int j = 0; j < 4; ++j) {
                int b = rr[j] >> BSH;
                int pos = bbase_s[b] + rank[k * 4 + j];
                if (pos < SCAP) {   // overflow guard (P ~ 1e-15)
                    unsigned pk = ((unsigned)(rr[j] & 255) << 17) | (unsigned)cc[j];
                    sorted[(size_t)b * SCAP + pos] = pk;
                }
            }
        }
    }
}

// ---- per-bucket fine CSR, node segments padded to x16 with sentinel col=NN ----
__global__ __launch_bounds__(256) void k_fine(const unsigned* __restrict__ sorted,
                                              const int* __restrict__ bcnt,
                                              int* __restrict__ csr_col,
                                              int* __restrict__ cnt_g,
                                              int2* __restrict__ se_g) {
    __shared__ int cnt_s[256];
    __shared__ int cur_s[256];
    __shared__ int sc[2][256];
    __shared__ int excl_s[256];
    int b = blockIdx.x;
    int tid = threadIdx.x;
    int s0 = b * SCAP;
    int e0 = s0 + min(bcnt[b], SCAP);
    int pbase = b * CCAP;
    cnt_s[tid] = 0;
    __syncthreads();
    for (int i = s0 + tid; i < e0; i += 256)
        atomicAdd(&cnt_s[sorted[i] >> 17], 1);
    __syncthreads();
    int cnt = cnt_s[tid];
    int pc = (cnt + 15) & ~15;          // pad to 16-entry multiple
    int cur = 0;
    sc[0][tid] = pc;
    __syncthreads();
    for (int s = 1; s < 256; s <<= 1) {
        sc[cur ^ 1][tid] = sc[cur][tid] + ((tid >= s) ? sc[cur][tid - s] : 0);
        cur ^= 1;
        __syncthreads();
    }
    int incl = sc[cur][tid];
    int excl = incl - pc;
    cur_s[tid] = excl;
    excl_s[tid] = excl;
    int nb = NN - b * 256;
    nb = nb > 256 ? 256 : nb;
    if (tid < nb) {
        int node = b * 256 + tid;
        cnt_g[node] = cnt;
        se_g[node] = make_int2(pbase + excl, pbase + excl + pc);   // padded segment
    }
    __syncthreads();
    for (int i = s0 + tid; i < e0; i += 256) {
        unsigned u = sorted[i];
        int p = atomicAdd(&cur_s[u >> 17], 1);
        csr_col[pbase + p] = (int)(u & 0x1FFFFu);
    }
    __syncthreads();
    if (tid < nb) {                      // fill padding with sentinel (h row NN = 0)
        int pc2 = (cnt_s[tid] + 15) & ~15;
        for (int i = cnt_s[tid]; i < pc2; ++i)
            csr_col[pbase + excl_s[tid] + i] = NN;
    }
}

// ---- k_baseh: base_bf = bf16(Xv@W1.T + deg*c); fused step-1
//      h8 = fp8((relu(base) @ W2.T) * S) via per-wave LDS transpose ----
__global__ __launch_bounds__(256) void k_baseh(
        const float* __restrict__ Xv, const unsigned short* __restrict__ w1b,
        const unsigned short* __restrict__ w2b,
        const int* __restrict__ cnt, const float* __restrict__ cvec,
        unsigned short* __restrict__ base_bf, unsigned char* __restrict__ h8) {
    __shared__ unsigned short etile[4][16][72];   // per-wave 16x64 bf16 tile (+pad)
    int wv = threadIdx.x >> 6;
    int wid = blockIdx.x * 4 + wv;
    int lane = threadIdx.x & 63;
    int m0 = wid * 16;
    if (m0 >= NN) return;
    int r = lane & 15, half = lane >> 4;
    const float* arow = Xv + (size_t)(m0 + r) * D + half * 8;
    f32x4 xa = *(const f32x4*)(arow);
    f32x4 xb = *(const f32x4*)(arow + 4);
    f32x4 xc = *(const f32x4*)(arow + 32);
    f32x4 xd = *(const f32x4*)(arow + 36);
    short8v a0, a1;
    #pragma unroll
    for (int j = 0; j < 4; ++j) {
        a0[j]     = (short)f2bf(xa[j]);
        a0[j + 4] = (short)f2bf(xb[j]);
        a1[j]     = (short)f2bf(xc[j]);
        a1[j + 4] = (short)f2bf(xd[j]);
    }
    int4 c4 = *(const int4*)(cnt + m0 + half * 4);
    float dg[4] = {(float)c4.x, (float)c4.y, (float)c4.z, (float)c4.w};
    #pragma unroll
    for (int t = 0; t < 4; ++t) {
        short8v b0 = *(const short8v*)(w1b + (size_t)(t * 16 + r) * D + half * 8);
        short8v b1 = *(const short8v*)(w1b + (size_t)(t * 16 + r) * D + 32 + half * 8);
        f32x4 cacc = {0.f, 0.f, 0.f, 0.f};
        cacc = __builtin_amdgcn_mfma_f32_16x16x32_bf16(a0, b0, cacc, 0, 0, 0);
        cacc = __builtin_amdgcn_mfma_f32_16x16x32_bf16(a1, b1, cacc, 0, 0, 0);
        float cv = cvec[t * 16 + r];
        #pragma unroll
        for (int q = 0; q < 4; ++q) {
            float s = cacc[q] + dg[q] * cv;
            size_t idx = (size_t)(m0 + half * 4 + q) * D + t * 16 + r;
            base_bf[idx] = f2bf(s);
            etile[wv][half * 4 + q][t * 16 + r] = f2bf(s > 0.f ? s : 0.f);
        }
    }
    // fused h (step 1): A-frags from LDS tile
    short8v ha0 = *(const short8v*)(&etile[wv][r][half * 8]);
    short8v ha1 = *(const short8v*)(&etile[wv][r][32 + half * 8]);
    #pragma unroll
    for (int t = 0; t < 4; ++t) {
        short8v b0 = *(const short8v*)(w2b + (size_t)(t * 16 + r) * D + half * 8);
        short8v b1 = *(const short8v*)(w2b + (size_t)(t * 16 + r) * D + 32 + half * 8);
        f32x4 cacc = {0.f, 0.f, 0.f, 0.f};
        cacc = __builtin_amdgcn_mfma_f32_16x16x32_bf16(ha0, b0, cacc, 0, 0, 0);
        cacc = __builtin_amdgcn_mfma_f32_16x16x32_bf16(ha1, b1, cacc, 0, 0, 0);
        #pragma unroll
        for (int q = 0; q < 4; ++q) {
            int pk = __builtin_amdgcn_cvt_pk_fp8_f32(cacc[q] * H_SCALE, 0.f, 0, false);
            h8[(size_t)(m0 + half * 4 + q) * D + t * 16 + r] = (unsigned char)(pk & 0xff);
        }
    }
}

// ---- fused pull+h: one block per 16-node tile, pure fast-path edge loop ----
// Segments are 16-padded with sentinel col=NN (h row NN == 0): no compares,
// no tail. One broadcast int4 index load + 4 unconditional gathers per trip.
template<int LAST>
__global__ __launch_bounds__(256) void k_pullh(
        const int2* __restrict__ se_g,
        const int* __restrict__ csr_col, const unsigned char* __restrict__ h_in,
        const unsigned short* __restrict__ base_bf,
        const unsigned short* __restrict__ w2b,
        unsigned char* __restrict__ h_out, float* __restrict__ out_f32) {
    __shared__ unsigned short etile[16][72];
    int tid = threadIdx.x;
    int wv = tid >> 6, lane = tid & 63;
    int q = lane >> 4, l = lane & 15;   // edge slot q (0..3), channel group l
    int m0 = blockIdx.x * 16;           // 6250 blocks, NN%16==0
    #pragma unroll
    for (int s = 0; s < 4; ++s) {
        int node = m0 + wv * 4 + s;
        int2 se = se_g[node];
        float a0 = 0.f, a1 = 0.f, a2 = 0.f, a3 = 0.f;
        for (int j = se.x; j < se.y; j += 16) {   // all-full trips
            int4 c = *(const int4*)(csr_col + j + 4 * q);   // 16B-aligned broadcast
            unsigned v0 = *((const unsigned*)(h_in + (size_t)c.x * D) + l);
            unsigned v1 = *((const unsigned*)(h_in + (size_t)c.y * D) + l);
            unsigned v2 = *((const unsigned*)(h_in + (size_t)c.z * D) + l);
            unsigned v3 = *((const unsigned*)(h_in + (size_t)c.w * D) + l);
            f32x2 f;
            f = __builtin_amdgcn_cvt_pk_f32_fp8(v0, false); a0 += f.x; a1 += f.y;
            f = __builtin_amdgcn_cvt_pk_f32_fp8(v0, true);  a2 += f.x; a3 += f.y;
            f = __builtin_amdgcn_cvt_pk_f32_fp8(v1, false); a0 += f.x; a1 += f.y;
            f = __builtin_amdgcn_cvt_pk_f32_fp8(v1, true);  a2 += f.x; a3 += f.y;
            f = __builtin_amdgcn_cvt_pk_f32_fp8(v2, false); a0 += f.x; a1 += f.y;
            f = __builtin_amdgcn_cvt_pk_f32_fp8(v2, true);  a2 += f.x; a3 += f.y;
            f = __builtin_amdgcn_cvt_pk_f32_fp8(v3, false); a0 += f.x; a1 += f.y;
            f = __builtin_amdgcn_cvt_pk_f32_fp8(v3, true);  a2 += f.x; a3 += f.y;
        }
        // fold the 4 edge slots (lane bits 4,5)
        a0 += __shfl_xor(a0, 16); a1 += __shfl_xor(a1, 16);
        a2 += __shfl_xor(a2, 16); a3 += __shfl_xor(a3, 16);
        a0 += __shfl_xor(a0, 32); a1 += __shfl_xor(a1, 32);
        a2 += __shfl_xor(a2, 32); a3 += __shfl_xor(a3, 32);
        if (q == 0) {
            ushort4v b4 = *(const ushort4v*)(base_bf + (size_t)node * D + l * 4);
            float r0 = fmaxf(fmaf(a0, H_ISCALE, bf2f(b4[0])), 0.f);
            float r1 = fmaxf(fmaf(a1, H_ISCALE, bf2f(b4[1])), 0.f);
            float r2 = fmaxf(fmaf(a2, H_ISCALE, bf2f(b4[2])), 0.f);
            float r3 = fmaxf(fmaf(a3, H_ISCALE, bf2f(b4[3])), 0.f);
            if (LAST) {
                f32x4 o4 = {r0, r1, r2, r3};
                *(f32x4*)(out_f32 + (size_t)node * D + l * 4) = o4;
            } else {
                ushort4v o4 = {f2bf(r0), f2bf(r1), f2bf(r2), f2bf(r3)};
                *(ushort4v*)(&etile[wv * 4 + s][l * 4]) = o4;
            }
        }
    }
    if (!LAST) {
        __syncthreads();
        // wave wv computes h-quadrant t = wv for the 16-node tile
        int r = lane & 15, half = lane >> 4;
        short8v ha0 = *(const short8v*)(&etile[r][half * 8]);
        short8v ha1 = *(const short8v*)(&etile[r][32 + half * 8]);
        int t = wv;
        short8v b0 = *(const short8v*)(w2b + (size_t)(t * 16 + r) * D + half * 8);
        short8v b1 = *(const short8v*)(w2b + (size_t)(t * 16 + r) * D + 32 + half * 8);
        f32x4 cacc = {0.f, 0.f, 0.f, 0.f};
        cacc = __builtin_amdgcn_mfma_f32_16x16x32_bf16(ha0, b0, cacc, 0, 0, 0);
        cacc = __builtin_amdgcn_mfma_f32_16x16x32_bf16(ha1, b1, cacc, 0, 0, 0);
        #pragma unroll
        for (int qq = 0; qq < 4; ++qq) {
            int pk = __builtin_amdgcn_cvt_pk_fp8_f32(cacc[qq] * H_SCALE, 0.f, 0, false);
            h_out[(size_t)(m0 + half * 4 + qq) * D + t * 16 + r] = (unsigned char)(pk & 0xff);
        }
    }
}

extern "C" void kernel_launch(void* const* d_in, const int* in_sizes, int n_in,
                              void* d_out, int out_size, void* d_ws, size_t ws_size,
                              hipStream_t stream) {
    const float* Xv = (const float*)d_in[0];
    const int*   ei = (const int*)d_in[1];
    const float* W1 = (const float*)d_in[2];
    const float* W2 = (const float*)d_in[3];
    const float* W3 = (const float*)d_in[4];
    const float* W4 = (const float*)d_in[5];

    char* ws = (char*)d_ws;
    size_t off = 0;
    unsigned short* base_bf = (unsigned short*)(ws + off); off += (size_t)NN * D * 2; // 12.8 MB
    unsigned char* h8a = (unsigned char*)(ws + off);   off += (size_t)(NN + 1) * D;  // +sentinel row
    unsigned char* h8b = (unsigned char*)(ws + off);   off += (size_t)(NN + 1) * D;
    off = (off + 15) & ~(size_t)15;
    int* csr_col = (int*)(ws + off);                   off += (size_t)NBKT * CCAP * 4; // 13.2 MB
    int* cnt     = (int*)(ws + off);                   off += (size_t)NN * 4;
    int2* se_g   = (int2*)(ws + off);                  off += (size_t)NN * 8;
    int* bcur    = (int*)(ws + off);                   off += NBKT * 4;
    float* cvec  = (float*)(ws + off);                 off += D * 4;
    unsigned short* w1b = (unsigned short*)(ws + off); off += D * D * 2;
    unsigned short* w2b = (unsigned short*)(ws + off); off += D * D * 2;
    off = (off + 15) & ~(size_t)15;
    unsigned* sorted = (unsigned*)(ws + off);          off += (size_t)NBKT * SCAP * 4; // 7.2 MB

    float* emb_f32 = (float*)d_out;

    const int* row = ei;
    const int* col = ei + NE;

    // ---- prep + fixed-capacity bucket sort + fine CSR (padded segments) ----
    k_prep<<<17, 256, 0, stream>>>(W1, W2, W3, W4, w1b, w2b, cvec, bcur, h8a, h8b);
    k_bucket<<<NBLK_E, 256, 0, stream>>>(row, col, bcur, sorted);
    k_fine<<<NBKT, 256, 0, stream>>>(sorted, bcur, csr_col, cnt, se_g);

    // ---- base + fused step-1 h ----
    k_baseh<<<(NN / 16 + 3) / 4, 256, 0, stream>>>(Xv, w1b, w2b, cnt, cvec,
                                                   base_bf, h8a);

    // ---- 3 message-passing steps, h fused into pull (ping-pong h buffers) ----
    k_pullh<0><<<NN / 16, 256, 0, stream>>>(se_g, csr_col, h8a, base_bf, w2b, h8b, nullptr);
    k_pullh<0><<<NN / 16, 256, 0, stream>>>(se_g, csr_col, h8b, base_bf, w2b, h8a, nullptr);
    k_pullh<1><<<NN / 16, 256, 0, stream>>>(se_g, csr_col, h8a, base_bf, w2b, nullptr, emb_f32);
}

// Round 17
// 178.300 us; speedup vs baseline: 1.5916x; 1.0008x over previous
//
#include <hip/hip_runtime.h>

#define NN 100000
#define NE 1600000
#define D  64
#define BSH 8                                  // bucket shift: 256 nodes/bucket
#define NBKT ((NN + 255) >> BSH)               // 391
#define NBLK_E ((NE / 4 + 1023) / 1024)        // 391 blocks, 1024 int4s each
#define SCAP 4608                              // sorted capacity/bucket (mean 4096 + 8 sigma)
#define CCAP 5376                              // csr capacity/bucket (4608 + 3*256 pad)
#define H_SCALE 256.0f
#define H_ISCALE 0.00390625f

typedef __attribute__((ext_vector_type(8))) short short8v;
typedef __attribute__((ext_vector_type(4))) unsigned short ushort4v;
typedef __attribute__((ext_vector_type(4))) float f32x4;
typedef __attribute__((ext_vector_type(2))) float f32x2;

__device__ __forceinline__ float bf2f(unsigned short x) {
    return __uint_as_float(((unsigned)x) << 16);
}
__device__ __forceinline__ unsigned short f2bf(float f) {  // RNE
    unsigned u = __float_as_uint(f);
    return (unsigned short)((u + 0x7fff + ((u >> 16) & 1)) >> 16);
}

// ---- fused prep: W1/W2 -> bf16, cvec, zero bcur, zero h sentinel rows ----
__global__ __launch_bounds__(256) void k_prep(
        const float* __restrict__ W1, const float* __restrict__ W2,
        const float* __restrict__ W3, const float* __restrict__ W4,
        unsigned short* __restrict__ w1b, unsigned short* __restrict__ w2b,
        float* __restrict__ cvec, int* __restrict__ bcur,
        unsigned char* __restrict__ h8a, unsigned char* __restrict__ h8b) {
    int b = blockIdx.x, tid = threadIdx.x;
    if (b < 16) {
        int i = b * 256 + tid;
        w1b[i] = f2bf(W1[i]);
        w2b[i] = f2bf(W2[i]);
    } else {
        for (int i = tid; i < NBKT; i += 256) bcur[i] = 0;
        if (tid < 16) ((unsigned*)(h8a + (size_t)NN * D))[tid] = 0;   // sentinel row = 0
        else if (tid < 32) ((unsigned*)(h8b + (size_t)NN * D))[tid - 16] = 0;
        if (tid < 64) {
            float s = 0.f;
            for (int k = 0; k < D; ++k) {
                float w4 = W4[k];
                s += W3[tid * D + k] * (w4 > 0.f ? w4 : 0.f);
            }
            cvec[tid] = s;
        }
    }
}

// ---- bucket-sort edges into fixed-capacity regions: sorted[b*SCAP + pos] ----
__global__ __launch_bounds__(256) void k_bucket(const int* __restrict__ row,
                                                const int* __restrict__ col,
                                                int* __restrict__ bcur,
                                                unsigned* __restrict__ sorted) {
    __shared__ int hist[NBKT];
    __shared__ int bbase_s[NBKT];
    int tid = threadIdx.x;
    for (int i = tid; i < NBKT; i += 256) hist[i] = 0;
    __syncthreads();
    int base4 = blockIdx.x * 1024;
    int4 r4[4], c4[4];
    int rank[16];
    bool valid[4];
    #pragma unroll
    for (int k = 0; k < 4; ++k) {
        int i4 = base4 + k * 256 + tid;
        valid[k] = (i4 < NE / 4);
        if (valid[k]) {
            r4[k] = ((const int4*)row)[i4];
            c4[k] = ((const int4*)col)[i4];
            rank[k * 4 + 0] = atomicAdd(&hist[r4[k].x >> BSH], 1);
            rank[k * 4 + 1] = atomicAdd(&hist[r4[k].y >> BSH], 1);
            rank[k * 4 + 2] = atomicAdd(&hist[r4[k].z >> BSH], 1);
            rank[k * 4 + 3] = atomicAdd(&hist[r4[k].w >> BSH], 1);
        }
    }
    __syncthreads();
    for (int i = tid; i < NBKT; i += 256)
        bbase_s[i] = hist[i] ? atomicAdd(&bcur[i], hist[i]) : 0;
    __syncthreads();
    #pragma unroll
    for (int k = 0; k < 4; ++k) {
        if (valid[k]) {
            int rr[4] = {r4[k].x, r4[k].y, r4[k].z, r4[k].w};
            int cc[4] = {c4[k].x, c4[k].y, c4[k].z, c4[k].w};
            #pragma unroll
            for (int j = 0; j < 4; ++j) {
                int b = rr[j] >> BSH;
                int pos = bbase_s[b] + rank[k * 4 + j];
                if (pos < SCAP) {   // overflow guard (P ~ 1e-15)
                    unsigned pk = ((unsigned)(rr[j] & 255) << 17) | (unsigned)cc[j];
                    sorted[(size_t)b * SCAP + pos] = pk;
                }
            }
        }
    }
}

// ---- per-bucket fine CSR, node segments padded to x4 with sentinel col=NN ----
__global__ __launch_bounds__(256) void k_fine(const unsigned* __restrict__ sorted,
                                              const int* __restrict__ bcnt,
                                              int* __restrict__ csr_col,
                                              int* __restrict__ cnt_g,
                                              int2* __restrict__ se_g) {
    __shared__ int cnt_s[256];
    __shared__ int cur_s[256];
    __shared__ int sc[2][256];
    __shared__ int excl_s[256];
    int b = blockIdx.x;
    int tid = threadIdx.x;
    int s0 = b * SCAP;
    int e0 = s0 + min(bcnt[b], SCAP);
    int pbase = b * CCAP;
    cnt_s[tid] = 0;
    __syncthreads();
    for (int i = s0 + tid; i < e0; i += 256)
        atomicAdd(&cnt_s[sorted[i] >> 17], 1);
    __syncthreads();
    int cnt = cnt_s[tid];
    int pc = (cnt + 3) & ~3;            // pad to 4-entry multiple
    int cur = 0;
    sc[0][tid] = pc;
    __syncthreads();
    for (int s = 1; s < 256; s <<= 1) {
        sc[cur ^ 1][tid] = sc[cur][tid] + ((tid >= s) ? sc[cur][tid - s] : 0);
        cur ^= 1;
        __syncthreads();
    }
    int incl = sc[cur][tid];
    int excl = incl - pc;
    cur_s[tid] = excl;
    excl_s[tid] = excl;
    int nb = NN - b * 256;
    nb = nb > 256 ? 256 : nb;
    if (tid < nb) {
        int node = b * 256 + tid;
        cnt_g[node] = cnt;
        se_g[node] = make_int2(pbase + excl, pbase + excl + pc);   // padded segment
    }
    __syncthreads();
    for (int i = s0 + tid; i < e0; i += 256) {
        unsigned u = sorted[i];
        int p = atomicAdd(&cur_s[u >> 17], 1);
        csr_col[pbase + p] = (int)(u & 0x1FFFFu);
    }
    __syncthreads();
    if (tid < nb) {                      // fill <=3 pad entries with sentinel (h row NN = 0)
        int c0 = cnt_s[tid];
        int pc2 = (c0 + 3) & ~3;
        for (int i = c0; i < pc2; ++i)
            csr_col[pbase + excl_s[tid] + i] = NN;
    }
}

// ---- k_baseh: base_bf = bf16(Xv@W1.T + deg*c); fused step-1
//      h8 = fp8((relu(base) @ W2.T) * S) via per-wave LDS transpose ----
__global__ __launch_bounds__(256) void k_baseh(
        const float* __restrict__ Xv, const unsigned short* __restrict__ w1b,
        const unsigned short* __restrict__ w2b,
        const int* __restrict__ cnt, const float* __restrict__ cvec,
        unsigned short* __restrict__ base_bf, unsigned char* __restrict__ h8) {
    __shared__ unsigned short etile[4][16][72];   // per-wave 16x64 bf16 tile (+pad)
    int wv = threadIdx.x >> 6;
    int wid = blockIdx.x * 4 + wv;
    int lane = threadIdx.x & 63;
    int m0 = wid * 16;
    if (m0 >= NN) return;
    int r = lane & 15, half = lane >> 4;
    const float* arow = Xv + (size_t)(m0 + r) * D + half * 8;
    f32x4 xa = *(const f32x4*)(arow);
    f32x4 xb = *(const f32x4*)(arow + 4);
    f32x4 xc = *(const f32x4*)(arow + 32);
    f32x4 xd = *(const f32x4*)(arow + 36);
    short8v a0, a1;
    #pragma unroll
    for (int j = 0; j < 4; ++j) {
        a0[j]     = (short)f2bf(xa[j]);
        a0[j + 4] = (short)f2bf(xb[j]);
        a1[j]     = (short)f2bf(xc[j]);
        a1[j + 4] = (short)f2bf(xd[j]);
    }
    int4 c4 = *(const int4*)(cnt + m0 + half * 4);
    float dg[4] = {(float)c4.x, (float)c4.y, (float)c4.z, (float)c4.w};
    #pragma unroll
    for (int t = 0; t < 4; ++t) {
        short8v b0 = *(const short8v*)(w1b + (size_t)(t * 16 + r) * D + half * 8);
        short8v b1 = *(const short8v*)(w1b + (size_t)(t * 16 + r) * D + 32 + half * 8);
        f32x4 cacc = {0.f, 0.f, 0.f, 0.f};
        cacc = __builtin_amdgcn_mfma_f32_16x16x32_bf16(a0, b0, cacc, 0, 0, 0);
        cacc = __builtin_amdgcn_mfma_f32_16x16x32_bf16(a1, b1, cacc, 0, 0, 0);
        float cv = cvec[t * 16 + r];
        #pragma unroll
        for (int q = 0; q < 4; ++q) {
            float s = cacc[q] + dg[q] * cv;
            size_t idx = (size_t)(m0 + half * 4 + q) * D + t * 16 + r;
            base_bf[idx] = f2bf(s);
            etile[wv][half * 4 + q][t * 16 + r] = f2bf(s > 0.f ? s : 0.f);
        }
    }
    // fused h (step 1): A-frags from LDS tile
    short8v ha0 = *(const short8v*)(&etile[wv][r][half * 8]);
    short8v ha1 = *(const short8v*)(&etile[wv][r][32 + half * 8]);
    #pragma unroll
    for (int t = 0; t < 4; ++t) {
        short8v b0 = *(const short8v*)(w2b + (size_t)(t * 16 + r) * D + half * 8);
        short8v b1 = *(const short8v*)(w2b + (size_t)(t * 16 + r) * D + 32 + half * 8);
        f32x4 cacc = {0.f, 0.f, 0.f, 0.f};
        cacc = __builtin_amdgcn_mfma_f32_16x16x32_bf16(ha0, b0, cacc, 0, 0, 0);
        cacc = __builtin_amdgcn_mfma_f32_16x16x32_bf16(ha1, b1, cacc, 0, 0, 0);
        #pragma unroll
        for (int q = 0; q < 4; ++q) {
            int pk = __builtin_amdgcn_cvt_pk_fp8_f32(cacc[q] * H_SCALE, 0.f, 0, false);
            h8[(size_t)(m0 + half * 4 + q) * D + t * 16 + r] = (unsigned char)(pk & 0xff);
        }
    }
}

// ---- fused pull+h: one block per 16-node tile ----
// Full 16-edge trips (no compares) + ONE guarded partial trip for the
// remaining 0-3 quads (1 predicate per slot). Segments padded to x4 with
// sentinel col=NN (h row NN == 0).
template<int LAST>
__global__ __launch_bounds__(256) void k_pullh(
        const int2* __restrict__ se_g,
        const int* __restrict__ csr_col, const unsigned char* __restrict__ h_in,
        const unsigned short* __restrict__ base_bf,
        const unsigned short* __restrict__ w2b,
        unsigned char* __restrict__ h_out, float* __restrict__ out_f32) {
    __shared__ unsigned short etile[16][72];
    int tid = threadIdx.x;
    int wv = tid >> 6, lane = tid & 63;
    int q = lane >> 4, l = lane & 15;   // edge slot q (0..3), channel group l
    int m0 = blockIdx.x * 16;           // 6250 blocks, NN%16==0
    #pragma unroll
    for (int s = 0; s < 4; ++s) {
        int node = m0 + wv * 4 + s;
        int2 se = se_g[node];
        float a0 = 0.f, a1 = 0.f, a2 = 0.f, a3 = 0.f;
        int j = se.x;
        for (; j + 16 <= se.y; j += 16) {   // full trips: no compares
            int4 c = *(const int4*)(csr_col + j + 4 * q);   // 16B-aligned broadcast
            unsigned v0 = *((const unsigned*)(h_in + (size_t)c.x * D) + l);
            unsigned v1 = *((const unsigned*)(h_in + (size_t)c.y * D) + l);
            unsigned v2 = *((const unsigned*)(h_in + (size_t)c.z * D) + l);
            unsigned v3 = *((const unsigned*)(h_in + (size_t)c.w * D) + l);
            f32x2 f;
            f = __builtin_amdgcn_cvt_pk_f32_fp8(v0, false); a0 += f.x; a1 += f.y;
            f = __builtin_amdgcn_cvt_pk_f32_fp8(v0, true);  a2 += f.x; a3 += f.y;
            f = __builtin_amdgcn_cvt_pk_f32_fp8(v1, false); a0 += f.x; a1 += f.y;
            f = __builtin_amdgcn_cvt_pk_f32_fp8(v1, true);  a2 += f.x; a3 += f.y;
            f = __builtin_amdgcn_cvt_pk_f32_fp8(v2, false); a0 += f.x; a1 += f.y;
            f = __builtin_amdgcn_cvt_pk_f32_fp8(v2, true);  a2 += f.x; a3 += f.y;
            f = __builtin_amdgcn_cvt_pk_f32_fp8(v3, false); a0 += f.x; a1 += f.y;
            f = __builtin_amdgcn_cvt_pk_f32_fp8(v3, true);  a2 += f.x; a3 += f.y;
        }
        if (4 * q < se.y - j) {             // partial trip: 1..3 quads, 1 predicate/slot
            int4 c = *(const int4*)(csr_col + j + 4 * q);
            unsigned v0 = *((const unsigned*)(h_in + (size_t)c.x * D) + l);
            unsigned v1 = *((const unsigned*)(h_in + (size_t)c.y * D) + l);
            unsigned v2 = *((const unsigned*)(h_in + (size_t)c.z * D) + l);
            unsigned v3 = *((const unsigned*)(h_in + (size_t)c.w * D) + l);
            f32x2 f;
            f = __builtin_amdgcn_cvt_pk_f32_fp8(v0, false); a0 += f.x; a1 += f.y;
            f = __builtin_amdgcn_cvt_pk_f32_fp8(v0, true);  a2 += f.x; a3 += f.y;
            f = __builtin_amdgcn_cvt_pk_f32_fp8(v1, false); a0 += f.x; a1 += f.y;
            f = __builtin_amdgcn_cvt_pk_f32_fp8(v1, true);  a2 += f.x; a3 += f.y;
            f = __builtin_amdgcn_cvt_pk_f32_fp8(v2, false); a0 += f.x; a1 += f.y;
            f = __builtin_amdgcn_cvt_pk_f32_fp8(v2, true);  a2 += f.x; a3 += f.y;
            f = __builtin_amdgcn_cvt_pk_f32_fp8(v3, false); a0 += f.x; a1 += f.y;
            f = __builtin_amdgcn_cvt_pk_f32_fp8(v3, true);  a2 += f.x; a3 += f.y;
        }
        // fold the 4 edge slots (lane bits 4,5)
        a0 += __shfl_xor(a0, 16); a1 += __shfl_xor(a1, 16);
        a2 += __shfl_xor(a2, 16); a3 += __shfl_xor(a3, 16);
        a0 += __shfl_xor(a0, 32); a1 += __shfl_xor(a1, 32);
        a2 += __shfl_xor(a2, 32); a3 += __shfl_xor(a3, 32);
        if (q == 0) {
            ushort4v b4 = *(const ushort4v*)(base_bf + (size_t)node * D + l * 4);
            float r0 = fmaxf(fmaf(a0, H_ISCALE, bf2f(b4[0])), 0.f);
            float r1 = fmaxf(fmaf(a1, H_ISCALE, bf2f(b4[1])), 0.f);
            float r2 = fmaxf(fmaf(a2, H_ISCALE, bf2f(b4[2])), 0.f);
            float r3 = fmaxf(fmaf(a3, H_ISCALE, bf2f(b4[3])), 0.f);
            if (LAST) {
                f32x4 o4 = {r0, r1, r2, r3};
                *(f32x4*)(out_f32 + (size_t)node * D + l * 4) = o4;
            } else {
                ushort4v o4 = {f2bf(r0), f2bf(r1), f2bf(r2), f2bf(r3)};
                *(ushort4v*)(&etile[wv * 4 + s][l * 4]) = o4;
            }
        }
    }
    if (!LAST) {
        __syncthreads();
        // wave wv computes h-quadrant t = wv for the 16-node tile
        int r = lane & 15, half = lane >> 4;
        short8v ha0 = *(const short8v*)(&etile[r][half * 8]);
        short8v ha1 = *(const short8v*)(&etile[r][32 + half * 8]);
        int t = wv;
        short8v b0 = *(const short8v*)(w2b + (size_t)(t * 16 + r) * D + half * 8);
        short8v b1 = *(const short8v*)(w2b + (size_t)(t * 16 + r) * D + 32 + half * 8);
        f32x4 cacc = {0.f, 0.f, 0.f, 0.f};
        cacc = __builtin_amdgcn_mfma_f32_16x16x32_bf16(ha0, b0, cacc, 0, 0, 0);
        cacc = __builtin_amdgcn_mfma_f32_16x16x32_bf16(ha1, b1, cacc, 0, 0, 0);
        #pragma unroll
        for (int qq = 0; qq < 4; ++qq) {
            int pk = __builtin_amdgcn_cvt_pk_fp8_f32(cacc[qq] * H_SCALE, 0.f, 0, false);
            h_out[(size_t)(m0 + half * 4 + qq) * D + t * 16 + r] = (unsigned char)(pk & 0xff);
        }
    }
}

extern "C" void kernel_launch(void* const* d_in, const int* in_sizes, int n_in,
                              void* d_out, int out_size, void* d_ws, size_t ws_size,
                              hipStream_t stream) {
    const float* Xv = (const float*)d_in[0];
    const int*   ei = (const int*)d_in[1];
    const float* W1 = (const float*)d_in[2];
    const float* W2 = (const float*)d_in[3];
    const float* W3 = (const float*)d_in[4];
    const float* W4 = (const float*)d_in[5];

    char* ws = (char*)d_ws;
    size_t off = 0;
    unsigned short* base_bf = (unsigned short*)(ws + off); off += (size_t)NN * D * 2; // 12.8 MB
    unsigned char* h8a = (unsigned char*)(ws + off);   off += (size_t)(NN + 1) * D;  // +sentinel row
    unsigned char* h8b = (unsigned char*)(ws + off);   off += (size_t)(NN + 1) * D;
    off = (off + 15) & ~(size_t)15;
    int* csr_col = (int*)(ws + off);                   off += (size_t)NBKT * CCAP * 4; // 8.4 MB
    int* cnt     = (int*)(ws + off);                   off += (size_t)NN * 4;
    int2* se_g   = (int2*)(ws + off);                  off += (size_t)NN * 8;
    int* bcur    = (int*)(ws + off);                   off += NBKT * 4;
    float* cvec  = (float*)(ws + off);                 off += D * 4;
    unsigned short* w1b = (unsigned short*)(ws + off); off += D * D * 2;
    unsigned short* w2b = (unsigned short*)(ws + off); off += D * D * 2;
    off = (off + 15) & ~(size_t)15;
    unsigned* sorted = (unsigned*)(ws + off);          off += (size_t)NBKT * SCAP * 4; // 7.2 MB

    float* emb_f32 = (float*)d_out;

    const int* row = ei;
    const int* col = ei + NE;

    // ---- prep + fixed-capacity bucket sort + fine CSR (x4-padded segments) ----
    k_prep<<<17, 256, 0, stream>>>(W1, W2, W3, W4, w1b, w2b, cvec, bcur, h8a, h8b);
    k_bucket<<<NBLK_E, 256, 0, stream>>>(row, col, bcur, sorted);
    k_fine<<<NBKT, 256, 0, stream>>>(sorted, bcur, csr_col, cnt, se_g);

    // ---- base + fused step-1 h ----
    k_baseh<<<(NN / 16 + 3) / 4, 256, 0, stream>>>(Xv, w1b, w2b, cnt, cvec,
                                                   base_bf, h8a);

    // ---- 3 message-passing steps, h fused into pull (ping-pong h buffers) ----
    k_pullh<0><<<NN / 16, 256, 0, stream>>>(se_g, csr_col, h8a, base_bf, w2b, h8b, nullptr);
    k_pullh<0><<<NN / 16, 256, 0, stream>>>(se_g, csr_col, h8b, base_bf, w2b, h8a, nullptr);
    k_pullh<1><<<NN / 16, 256, 0, stream>>>(se_g, csr_col, h8a, base_bf, w2b, nullptr, emb_f32);
}